// Round 1
// baseline (590.491 us; speedup 1.0000x reference)
//
#include <hip/hip_runtime.h>
#include <hip/hip_bf16.h>
#include <stdint.h>

#define B_ 4
#define C_ 384
#define H_ 128
#define W_ 128
#define L_ (H_*W_)      // 16384
#define NH 8
#define DH 48           // C_/NH
#define NPOS (B_*L_)    // 65536
#define SPLIT 8

typedef __attribute__((ext_vector_type(8))) short bf16x8;
typedef __attribute__((ext_vector_type(4))) float f32x4;
typedef unsigned short u16;
typedef unsigned int u32;

__device__ __forceinline__ float bf2f(u16 v){
  union { float f; u32 u; } x; x.u = ((u32)v) << 16; return x.f;
}
__device__ __forceinline__ u16 f2bf(float f){
  __hip_bfloat16 h = __float2bfloat16(f);
  return *reinterpret_cast<u16*>(&h);
}

#define GLOAD_LDS16(g, l) \
  __builtin_amdgcn_global_load_lds((const __attribute__((address_space(1))) u32*)(g), \
                                   (__attribute__((address_space(3))) u32*)(l), 16, 0, 0)

// ---------------- K0: convert 1x1 conv weights to bf16, concat [1152][384] ----------------
__global__ __launch_bounds__(256) void k_cvt_w(const float* __restrict__ wq,
                                               const float* __restrict__ wk,
                                               const float* __restrict__ wv,
                                               u16* __restrict__ wc){
  int i = blockIdx.x * 256 + threadIdx.x;
  if (i >= 3*C_*C_) return;
  int m = i / C_;
  int c = i - m*C_;
  const float* src = (m < C_) ? wq : (m < 2*C_) ? wk : wv;
  int mm = (m >= 2*C_) ? m - 2*C_ : (m >= C_) ? m - C_ : m;
  wc[i] = f2bf(src[mm*C_ + c]);
}

// ---------------- K1: LayerNorm over C, write transposed bf16 [B*L][C] ----------------
__global__ __launch_bounds__(256) void k_ln1(const float* __restrict__ x,
                                             const float* __restrict__ w,
                                             const float* __restrict__ b,
                                             u16* __restrict__ xt){
  int bb = blockIdx.x >> 6;
  int l  = ((blockIdx.x & 63) << 8) + threadIdx.x;
  const float* xp = x + (size_t)bb*C_*L_ + l;
  float s = 0.f, s2 = 0.f;
  for (int c = 0; c < C_; ++c){ float v = xp[(size_t)c*L_]; s += v; s2 += v*v; }
  float mu = s * (1.f/C_);
  float var = s2 * (1.f/C_) - mu*mu;
  float rstd = rsqrtf(var + 1e-5f);
  u16* dst = xt + ((size_t)bb*L_ + l) * C_;
  for (int c = 0; c < C_; c += 8){
    uint4 pack;
    u16* tp = reinterpret_cast<u16*>(&pack);
    #pragma unroll
    for (int j = 0; j < 8; ++j){
      float v = xp[(size_t)(c+j)*L_];
      tp[j] = f2bf((v - mu) * rstd * w[c+j] + b[c+j]);
    }
    *reinterpret_cast<uint4*>(dst + c) = pack;
  }
}

// ---------------- K2: GEMM qkv = Wc[1152x384] * xt^T -> [3][B][C][L] bf16 ----------------
__global__ __launch_bounds__(256) void k_gemm(const u16* __restrict__ Wc,
                                              const u16* __restrict__ Xt,
                                              u16* __restrict__ qkv){
  __shared__ u16 As[128*32];
  __shared__ u16 Bs[128*32];
  const int tid = threadIdx.x;
  const int bm = blockIdx.x % 9;
  const int bn = blockIdx.x / 9;
  const int m0 = bm * 128;
  const int n0 = bn * 128;
  const int w = tid >> 6, lane = tid & 63;
  const int wm = (w >> 1) * 64, wn = (w & 1) * 64;
  const int fr = lane & 15, kq = (lane >> 4) * 8;

  f32x4 acc[4][4] = {};

  for (int k0 = 0; k0 < 384; k0 += 32){
    #pragma unroll
    for (int i = 0; i < 2; ++i){
      int idx = i*256 + tid;          // 0..511, 16B each
      int row = idx >> 2, q = idx & 3;
      GLOAD_LDS16(Wc + (size_t)(m0+row)*384 + k0 + q*8, As + idx*8);
      GLOAD_LDS16(Xt + (size_t)(n0+row)*384 + k0 + q*8, Bs + idx*8);
    }
    __syncthreads();
    bf16x8 af[4], bfm[4];
    #pragma unroll
    for (int i = 0; i < 4; ++i)
      af[i] = *reinterpret_cast<const bf16x8*>(As + (wm + i*16 + fr)*32 + kq);
    #pragma unroll
    for (int j = 0; j < 4; ++j)
      bfm[j] = *reinterpret_cast<const bf16x8*>(Bs + (wn + j*16 + fr)*32 + kq);
    #pragma unroll
    for (int i = 0; i < 4; ++i)
      #pragma unroll
      for (int j = 0; j < 4; ++j)
        acc[i][j] = __builtin_amdgcn_mfma_f32_16x16x32_bf16(af[i], bfm[j], acc[i][j], 0, 0, 0);
    __syncthreads();
  }

  #pragma unroll
  for (int i = 0; i < 4; ++i){
    int mbase = m0 + wm + i*16 + (lane >> 4) * 4;
    #pragma unroll
    for (int j = 0; j < 4; ++j){
      int n = n0 + wn + j*16 + fr;
      int bb = n >> 14, l = n & (L_-1);
      #pragma unroll
      for (int r = 0; r < 4; ++r){
        int m = mbase + r;
        int proj = (m >= 2*C_) ? 2 : (m >= C_) ? 1 : 0;
        int c = m - proj*C_;
        qkv[(((size_t)proj*B_ + bb)*C_ + c)*L_ + l] = f2bf(acc[i][j][r]);
      }
    }
  }
}

// ---------------- K3: depthwise 3x3 in-place + per-channel sumsq for q,k ----------------
__global__ __launch_bounds__(256) void k_dwconv(u16* __restrict__ qkv,
                                                const float* __restrict__ dwq,
                                                const float* __restrict__ dwk,
                                                const float* __restrict__ dwv,
                                                float* __restrict__ sumsq){
  __shared__ u16 pl[128*128];
  int pid = blockIdx.x;                  // t*B*C + b*C + c
  int t = pid / (B_*C_);
  int bc = pid - t*(B_*C_);
  int c = bc % C_;
  const float* dw = ((t == 0) ? dwq : (t == 1) ? dwk : dwv) + c*9;
  u16* plane = qkv + ((size_t)t*B_*C_ + bc) * L_;
  int tid = threadIdx.x;
  #pragma unroll
  for (int i = 0; i < 8; ++i){
    int idx = i*256 + tid;
    *reinterpret_cast<uint4*>(pl + idx*8) = *reinterpret_cast<const uint4*>(plane + idx*8);
  }
  float wgt[9];
  #pragma unroll
  for (int i = 0; i < 9; ++i) wgt[i] = dw[i];
  __syncthreads();
  float ss = 0.f;
  for (int p = 0; p < 64; ++p){
    int pix = p*256 + tid;
    int y = pix >> 7, xx0 = pix & 127;
    float a = 0.f;
    #pragma unroll
    for (int dy = -1; dy <= 1; ++dy){
      int yy = y + dy;
      if (yy < 0 || yy > 127) continue;
      #pragma unroll
      for (int dx = -1; dx <= 1; ++dx){
        int xx = xx0 + dx;
        if (xx < 0 || xx > 127) continue;
        a += wgt[(dy+1)*3 + (dx+1)] * bf2f(pl[yy*128 + xx]);
      }
    }
    plane[pix] = f2bf(a);
    ss += a * a;
  }
  if (t < 2){
    #pragma unroll
    for (int off = 32; off > 0; off >>= 1) ss += __shfl_down(ss, off);
    __shared__ float red[4];
    if ((tid & 63) == 0) red[tid >> 6] = ss;
    __syncthreads();
    if (tid == 0) sumsq[t*(B_*C_) + bc] = red[0] + red[1] + red[2] + red[3];
  }
}

// ---------------- K4: attention logits (split-K over L), S_part[s][b][n][48][48] ----------------
__global__ __launch_bounds__(256) void k_qk(const u16* __restrict__ qkv,
                                            float* __restrict__ Spart){
  int gid = blockIdx.x;                 // (s*B + b)*NH + n
  int s = gid / (B_*NH);
  int bn = gid - s*(B_*NH);
  int b = bn / NH, n = bn - b*NH;
  const u16* qb = qkv + ((size_t)b*C_ + n*DH) * L_;
  const u16* kb = qkv + ((size_t)B_*C_ + (size_t)b*C_ + n*DH) * L_;
  int tid = threadIdx.x, w = tid >> 6, lane = tid & 63;
  int fr = lane & 15, kq = (lane >> 4) * 8;
  int l0 = s * (L_/SPLIT) + w * (L_/SPLIT/4);     // 2048/block, 512/wave
  f32x4 acc[3][3] = {};
  for (int kk = 0; kk < 512; kk += 32){
    int koff = l0 + kk + kq;
    bf16x8 af[3], bfm[3];
    #pragma unroll
    for (int i = 0; i < 3; ++i) af[i]  = *reinterpret_cast<const bf16x8*>(qb + (size_t)(i*16+fr)*L_ + koff);
    #pragma unroll
    for (int j = 0; j < 3; ++j) bfm[j] = *reinterpret_cast<const bf16x8*>(kb + (size_t)(j*16+fr)*L_ + koff);
    #pragma unroll
    for (int i = 0; i < 3; ++i)
      #pragma unroll
      for (int j = 0; j < 3; ++j)
        acc[i][j] = __builtin_amdgcn_mfma_f32_16x16x32_bf16(af[i], bfm[j], acc[i][j], 0, 0, 0);
  }
  __shared__ float red[48*48];
  for (int ww = 0; ww < 4; ++ww){
    if (w == ww){
      #pragma unroll
      for (int i = 0; i < 3; ++i)
        #pragma unroll
        for (int j = 0; j < 3; ++j)
          #pragma unroll
          for (int r = 0; r < 4; ++r){
            int row = i*16 + (lane >> 4)*4 + r;
            int col = j*16 + fr;
            if (ww == 0) red[row*48 + col] = acc[i][j][r];
            else         red[row*48 + col] += acc[i][j][r];
          }
    }
    __syncthreads();
  }
  float* dst = Spart + ((size_t)gid) * 2304;
  for (int idx = tid; idx < 2304; idx += 256) dst[idx] = red[idx];
}

// ---------------- K5: reduce split-K, fold L2 norms + scale, softmax ----------------
__global__ void k_softmax(const float* __restrict__ Spart,
                          const float* __restrict__ sumsq,
                          const float* __restrict__ scale,
                          float* __restrict__ attn){
  int bn = blockIdx.x;                  // b*NH + n
  int b = bn / NH, n = bn - b*NH;
  int i = threadIdx.x;
  if (i >= DH) return;
  const float* sq = sumsq + (size_t)b*C_ + n*DH;
  const float* sk = sumsq + (size_t)B_*C_ + (size_t)b*C_ + n*DH;
  float nq = fmaxf(sqrtf(sq[i]), 1e-12f);
  float sc = scale[n];
  float row[48];
  #pragma unroll
  for (int j = 0; j < DH; ++j){
    float acc = 0.f;
    #pragma unroll
    for (int s = 0; s < SPLIT; ++s)
      acc += Spart[((size_t)(s*(B_*NH) + bn))*2304 + i*48 + j];
    float nk = fmaxf(sqrtf(sk[j]), 1e-12f);
    row[j] = acc / (nq * nk) * sc;
  }
  float m = row[0];
  #pragma unroll
  for (int j = 1; j < DH; ++j) m = fmaxf(m, row[j]);
  float sum = 0.f;
  #pragma unroll
  for (int j = 0; j < DH; ++j){ row[j] = __expf(row[j] - m); sum += row[j]; }
  float inv = 1.f / sum;
  float* dst = attn + ((size_t)bn)*2304 + i*48;
  #pragma unroll
  for (int j = 0; j < DH; ++j) dst[j] = row[j] * inv;
}

// ---------------- K6: out = attn @ v, then LayerNorm over C, write f32 ----------------
__global__ __launch_bounds__(256) void k_av_ln2(const u16* __restrict__ qkv,
                                                const float* __restrict__ attn,
                                                const float* __restrict__ w2,
                                                const float* __restrict__ b2,
                                                float* __restrict__ out){
  __shared__ float At[NH*2304];        // 73.7 KB
  int bb = blockIdx.x >> 6;
  int l = ((blockIdx.x & 63) << 8) + threadIdx.x;
  const float* asrc = attn + (size_t)bb*NH*2304;
  for (int idx = threadIdx.x; idx < NH*2304; idx += 256) At[idx] = asrc[idx];
  __syncthreads();
  const u16* vb = qkv + ((size_t)2*B_*C_ + (size_t)bb*C_) * L_ + l;
  float s = 0.f, s2 = 0.f;
  for (int n = 0; n < NH; ++n){
    float vv[DH];
    #pragma unroll
    for (int e = 0; e < DH; ++e) vv[e] = bf2f(vb[(size_t)(n*DH+e)*L_]);
    const float* A = At + n*2304;
    for (int d = 0; d < DH; ++d){
      float o = 0.f;
      #pragma unroll
      for (int e = 0; e < DH; ++e) o += A[d*48+e] * vv[e];
      s += o; s2 += o*o;
    }
  }
  float mu = s * (1.f/C_);
  float rstd = rsqrtf(s2 * (1.f/C_) - mu*mu + 1e-5f);
  float* op = out + (size_t)bb*C_*L_ + l;
  for (int n = 0; n < NH; ++n){
    float vv[DH];
    #pragma unroll
    for (int e = 0; e < DH; ++e) vv[e] = bf2f(vb[(size_t)(n*DH+e)*L_]);
    const float* A = At + n*2304;
    for (int d = 0; d < DH; ++d){
      float o = 0.f;
      #pragma unroll
      for (int e = 0; e < DH; ++e) o += A[d*48+e] * vv[e];
      int c = n*DH + d;
      op[(size_t)c*L_] = (o - mu) * rstd * w2[c] + b2[c];
    }
  }
}

extern "C" void kernel_launch(void* const* d_in, const int* in_sizes, int n_in,
                              void* d_out, int out_size, void* d_ws, size_t ws_size,
                              hipStream_t stream){
  const float* x     = (const float*)d_in[0];
  const float* wq    = (const float*)d_in[1];
  const float* wk    = (const float*)d_in[2];
  const float* wv    = (const float*)d_in[3];
  const float* dwq   = (const float*)d_in[4];
  const float* dwk   = (const float*)d_in[5];
  const float* dwv   = (const float*)d_in[6];
  const float* scale = (const float*)d_in[7];
  const float* ln1w  = (const float*)d_in[8];
  const float* ln1b  = (const float*)d_in[9];
  const float* ln2w  = (const float*)d_in[10];
  const float* ln2b  = (const float*)d_in[11];
  float* out = (float*)d_out;

  char* ws = (char*)d_ws;
  u16*   qkv   = (u16*)ws;                          // [3][B][C][L] bf16  = 150,994,944 B
  u16*   xt    = (u16*)(ws + 150994944);            // [B*L][C] bf16     =  50,331,648 B
  u16*   wc    = (u16*)(ws + 201326592);            // [1152][384] bf16  =     884,736 B
  float* sumsq = (float*)(ws + 202211328);          // [2][B*C] f32      =      12,288 B
  float* Spart = (float*)(ws + 202223616);          // [8][32][2304] f32 =   2,359,296 B
  float* attn  = (float*)(ws + 204582912);          // [32][2304] f32    =     294,912 B

  k_cvt_w  <<<1728, 256, 0, stream>>>(wq, wk, wv, wc);
  k_ln1    <<<256, 256, 0, stream>>>(x, ln1w, ln1b, xt);
  k_gemm   <<<9*512, 256, 0, stream>>>(wc, xt, qkv);
  k_dwconv <<<3*B_*C_, 256, 0, stream>>>(qkv, dwq, dwk, dwv, sumsq);
  k_qk     <<<SPLIT*B_*NH, 256, 0, stream>>>(qkv, Spart);
  k_softmax<<<B_*NH, 64, 0, stream>>>(Spart, sumsq, scale, attn);
  k_av_ln2 <<<256, 256, 0, stream>>>(qkv, attn, ln2w, ln2b, out);
}

// Round 3
// 490.386 us; speedup vs baseline: 1.2041x; 1.2041x over previous
//
#include <hip/hip_runtime.h>
#include <hip/hip_bf16.h>
#include <stdint.h>

#define B_ 4
#define C_ 384
#define H_ 128
#define W_ 128
#define L_ (H_*W_)      // 16384
#define NH 8
#define DH 48           // C_/NH
#define SPLIT 8

typedef __attribute__((ext_vector_type(8))) short bf16x8;
typedef __attribute__((ext_vector_type(4))) float f32x4;
typedef unsigned short u16;
typedef unsigned int u32;

__device__ __forceinline__ float bf2f(u16 v){
  union { float f; u32 u; } x; x.u = ((u32)v) << 16; return x.f;
}
__device__ __forceinline__ u16 f2bf(float f){
  __hip_bfloat16 h = __float2bfloat16(f);
  return *reinterpret_cast<u16*>(&h);
}

#define GLOAD_LDS16(g, l) \
  __builtin_amdgcn_global_load_lds((const __attribute__((address_space(1))) u32*)(g), \
                                   (__attribute__((address_space(3))) u32*)(l), 16, 0, 0)

// ---------------- K0: convert 1x1 conv weights to bf16, concat [1152][384] ----------------
__global__ __launch_bounds__(256) void k_cvt_w(const float* __restrict__ wq,
                                               const float* __restrict__ wk,
                                               const float* __restrict__ wv,
                                               u16* __restrict__ wc){
  int i = blockIdx.x * 256 + threadIdx.x;
  if (i >= 3*C_*C_) return;
  int m = i / C_;
  int c = i - m*C_;
  const float* src = (m < C_) ? wq : (m < 2*C_) ? wk : wv;
  int mm = (m >= 2*C_) ? m - 2*C_ : (m >= C_) ? m - C_ : m;
  wc[i] = f2bf(src[mm*C_ + c]);
}

// ---------------- K1: LayerNorm over C, write transposed bf16 [B*L][C] ----------------
__global__ __launch_bounds__(256) void k_ln1(const float* __restrict__ x,
                                             const float* __restrict__ w,
                                             const float* __restrict__ b,
                                             u16* __restrict__ xt){
  int bb = blockIdx.x >> 6;
  int l  = ((blockIdx.x & 63) << 8) + threadIdx.x;
  const float* xp = x + (size_t)bb*C_*L_ + l;
  float s = 0.f, s2 = 0.f;
  for (int c = 0; c < C_; ++c){ float v = xp[(size_t)c*L_]; s += v; s2 += v*v; }
  float mu = s * (1.f/C_);
  float var = s2 * (1.f/C_) - mu*mu;
  float rstd = rsqrtf(var + 1e-5f);
  u16* dst = xt + ((size_t)bb*L_ + l) * C_;
  for (int c = 0; c < C_; c += 8){
    uint4 pack;
    u16* tp = reinterpret_cast<u16*>(&pack);
    #pragma unroll
    for (int j = 0; j < 8; ++j){
      float v = xp[(size_t)(c+j)*L_];
      tp[j] = f2bf((v - mu) * rstd * w[c+j] + b[c+j]);
    }
    *reinterpret_cast<uint4*>(dst + c) = pack;
  }
}

// ---------------- K2: GEMM qkv = Wc[1152x384] * xt^T -> [3][B][C][L] bf16 ----------------
__global__ __launch_bounds__(256) void k_gemm(const u16* __restrict__ Wc,
                                              const u16* __restrict__ Xt,
                                              u16* __restrict__ qkv){
  __shared__ u16 As[128*32];
  __shared__ u16 Bs[128*32];
  const int tid = threadIdx.x;
  const int bm = blockIdx.x % 9;
  const int bn = blockIdx.x / 9;
  const int m0 = bm * 128;
  const int n0 = bn * 128;
  const int w = tid >> 6, lane = tid & 63;
  const int wm = (w >> 1) * 64, wn = (w & 1) * 64;
  const int fr = lane & 15, kq = (lane >> 4) * 8;

  f32x4 acc[4][4] = {};

  for (int k0 = 0; k0 < 384; k0 += 32){
    #pragma unroll
    for (int i = 0; i < 2; ++i){
      int idx = i*256 + tid;          // 0..511, 16B each
      int row = idx >> 2, q = idx & 3;
      GLOAD_LDS16(Wc + (size_t)(m0+row)*384 + k0 + q*8, As + idx*8);
      GLOAD_LDS16(Xt + (size_t)(n0+row)*384 + k0 + q*8, Bs + idx*8);
    }
    __syncthreads();
    bf16x8 af[4], bfm[4];
    #pragma unroll
    for (int i = 0; i < 4; ++i)
      af[i] = *reinterpret_cast<const bf16x8*>(As + (wm + i*16 + fr)*32 + kq);
    #pragma unroll
    for (int j = 0; j < 4; ++j)
      bfm[j] = *reinterpret_cast<const bf16x8*>(Bs + (wn + j*16 + fr)*32 + kq);
    #pragma unroll
    for (int i = 0; i < 4; ++i)
      #pragma unroll
      for (int j = 0; j < 4; ++j)
        acc[i][j] = __builtin_amdgcn_mfma_f32_16x16x32_bf16(af[i], bfm[j], acc[i][j], 0, 0, 0);
    __syncthreads();
  }

  #pragma unroll
  for (int i = 0; i < 4; ++i){
    int mbase = m0 + wm + i*16 + (lane >> 4) * 4;
    #pragma unroll
    for (int j = 0; j < 4; ++j){
      int n = n0 + wn + j*16 + fr;
      int bb = n >> 14, l = n & (L_-1);
      #pragma unroll
      for (int r = 0; r < 4; ++r){
        int m = mbase + r;
        int proj = (m >= 2*C_) ? 2 : (m >= C_) ? 1 : 0;
        int c = m - proj*C_;
        qkv[(((size_t)proj*B_ + bb)*C_ + c)*L_ + l] = f2bf(acc[i][j][r]);
      }
    }
  }
}

// ---------------- K3: depthwise 3x3 in-place + per-channel sumsq for q,k ----------------
__global__ __launch_bounds__(256) void k_dwconv(u16* __restrict__ qkv,
                                                const float* __restrict__ dwq,
                                                const float* __restrict__ dwk,
                                                const float* __restrict__ dwv,
                                                float* __restrict__ sumsq){
  __shared__ u16 pl[128*128];
  int pid = blockIdx.x;                  // t*B*C + b*C + c
  int t = pid / (B_*C_);
  int bc = pid - t*(B_*C_);
  int c = bc % C_;
  const float* dw = ((t == 0) ? dwq : (t == 1) ? dwk : dwv) + c*9;
  u16* plane = qkv + ((size_t)t*B_*C_ + bc) * L_;
  int tid = threadIdx.x;
  #pragma unroll
  for (int i = 0; i < 8; ++i){
    int idx = i*256 + tid;
    *reinterpret_cast<uint4*>(pl + idx*8) = *reinterpret_cast<const uint4*>(plane + idx*8);
  }
  float wgt[9];
  #pragma unroll
  for (int i = 0; i < 9; ++i) wgt[i] = dw[i];
  __syncthreads();
  float ss = 0.f;
  for (int p = 0; p < 64; ++p){
    int pix = p*256 + tid;
    int y = pix >> 7, xx0 = pix & 127;
    float a = 0.f;
    #pragma unroll
    for (int dy = -1; dy <= 1; ++dy){
      int yy = y + dy;
      if (yy < 0 || yy > 127) continue;
      #pragma unroll
      for (int dx = -1; dx <= 1; ++dx){
        int xx = xx0 + dx;
        if (xx < 0 || xx > 127) continue;
        a += wgt[(dy+1)*3 + (dx+1)] * bf2f(pl[yy*128 + xx]);
      }
    }
    plane[pix] = f2bf(a);
    ss += a * a;
  }
  if (t < 2){
    #pragma unroll
    for (int off = 32; off > 0; off >>= 1) ss += __shfl_down(ss, off);
    __shared__ float red[4];
    if ((tid & 63) == 0) red[tid >> 6] = ss;
    __syncthreads();
    if (tid == 0) sumsq[t*(B_*C_) + bc] = red[0] + red[1] + red[2] + red[3];
  }
}

// ---------------- K4: attention logits (split-K over L), S_part[s][b][n][48][48] ----------------
__global__ __launch_bounds__(256) void k_qk(const u16* __restrict__ qkv,
                                            float* __restrict__ Spart){
  int gid = blockIdx.x;                 // (s*B + b)*NH + n
  int s = gid / (B_*NH);
  int bn = gid - s*(B_*NH);
  int b = bn / NH, n = bn - b*NH;
  const u16* qb = qkv + ((size_t)b*C_ + n*DH) * L_;
  const u16* kb = qkv + ((size_t)B_*C_ + (size_t)b*C_ + n*DH) * L_;
  int tid = threadIdx.x, w = tid >> 6, lane = tid & 63;
  int fr = lane & 15, kq = (lane >> 4) * 8;
  int l0 = s * (L_/SPLIT) + w * (L_/SPLIT/4);     // 2048/block, 512/wave
  f32x4 acc[3][3] = {};
  for (int kk = 0; kk < 512; kk += 32){
    int koff = l0 + kk + kq;
    bf16x8 af[3], bfm[3];
    #pragma unroll
    for (int i = 0; i < 3; ++i) af[i]  = *reinterpret_cast<const bf16x8*>(qb + (size_t)(i*16+fr)*L_ + koff);
    #pragma unroll
    for (int j = 0; j < 3; ++j) bfm[j] = *reinterpret_cast<const bf16x8*>(kb + (size_t)(j*16+fr)*L_ + koff);
    #pragma unroll
    for (int i = 0; i < 3; ++i)
      #pragma unroll
      for (int j = 0; j < 3; ++j)
        acc[i][j] = __builtin_amdgcn_mfma_f32_16x16x32_bf16(af[i], bfm[j], acc[i][j], 0, 0, 0);
  }
  __shared__ float red[48*48];
  for (int ww = 0; ww < 4; ++ww){
    if (w == ww){
      #pragma unroll
      for (int i = 0; i < 3; ++i)
        #pragma unroll
        for (int j = 0; j < 3; ++j)
          #pragma unroll
          for (int r = 0; r < 4; ++r){
            int row = i*16 + (lane >> 4)*4 + r;
            int col = j*16 + fr;
            if (ww == 0) red[row*48 + col] = acc[i][j][r];
            else         red[row*48 + col] += acc[i][j][r];
          }
    }
    __syncthreads();
  }
  float* dst = Spart + ((size_t)gid) * 2304;
  for (int idx = tid; idx < 2304; idx += 256) dst[idx] = red[idx];
}

// ---------------- K5: reduce split-K, fold L2 norms + scale, softmax -> bf16 hi|lo [d][96] ----------------
__global__ void k_softmax(const float* __restrict__ Spart,
                          const float* __restrict__ sumsq,
                          const float* __restrict__ scale,
                          u16* __restrict__ attn96){
  int bn = blockIdx.x;                  // b*NH + n
  int b = bn / NH, n = bn - b*NH;
  int i = threadIdx.x;
  if (i >= DH) return;
  const float* sq = sumsq + (size_t)b*C_ + n*DH;
  const float* sk = sumsq + (size_t)B_*C_ + (size_t)b*C_ + n*DH;
  float nq = fmaxf(sqrtf(sq[i]), 1e-12f);
  float sc = scale[n];
  float row[48];
  #pragma unroll
  for (int j = 0; j < DH; ++j){
    float acc = 0.f;
    #pragma unroll
    for (int s = 0; s < SPLIT; ++s)
      acc += Spart[((size_t)(s*(B_*NH) + bn))*2304 + i*48 + j];
    float nk = fmaxf(sqrtf(sk[j]), 1e-12f);
    row[j] = acc / (nq * nk) * sc;
  }
  float m = row[0];
  #pragma unroll
  for (int j = 1; j < DH; ++j) m = fmaxf(m, row[j]);
  float sum = 0.f;
  #pragma unroll
  for (int j = 0; j < DH; ++j){ row[j] = __expf(row[j] - m); sum += row[j]; }
  float inv = 1.f / sum;
  u16* dst = attn96 + ((size_t)bn)*DH*96 + i*96;     // row d=i: hi[0..48) | lo[48..96)
  #pragma unroll
  for (int j = 0; j < DH; ++j){
    float a = row[j] * inv;
    u16 hi = f2bf(a);
    float lo = a - bf2f(hi);
    dst[j]      = hi;
    dst[48 + j] = f2bf(lo);
  }
}

// ---------------- K6: out = attn @ v via MFMA (hi+lo split-K=96), fused LayerNorm ----------------
// Block: 64-pixel tile x all 384 channels. Wave w owns pixels [16w,16w+16).
// LDS: v transposed [64 px][384 ch] bf16, row stride 784B + extra 16B pad per 8 rows.
// No XOR swizzle: stride 784 (=16 mod 128) spreads the b128 fragment reads uniformly
// over all banks; the (p>>3)*16 pad de-conflicts the transposed write side.
#define VT_STRIDE 784
__device__ __forceinline__ int vt_off(int p, int ch){
  return p*VT_STRIDE + ((p>>3)<<4) + 2*ch;
}
__global__ __launch_bounds__(256) void k_av_ln2(const u16* __restrict__ qkv,
                                                const u16* __restrict__ attn96,
                                                const float* __restrict__ w2,
                                                const float* __restrict__ b2,
                                                float* __restrict__ out){
  __shared__ u16 vt[(64*VT_STRIDE + 8*16)/2];     // 50304 B
  char* vtb = reinterpret_cast<char*>(vt);
  const int tid = threadIdx.x;
  const int bb = blockIdx.x >> 8;        // 256 tiles per batch
  const int l0 = (blockIdx.x & 255) << 6;
  const u16* vg = qkv + ((size_t)2*B_*C_ + (size_t)bb*C_)*L_ + l0;

  // stage v[c][l0..l0+63] -> vt[p][c] (transposed): channel-pairs, u32 writes
  #pragma unroll
  for (int it = 0; it < 6; ++it){
    int idx = it*256 + tid;            // 0..1535
    int cp = idx >> 3, g = idx & 7;    // cp: channel pair 0..191, g: pixel group
    int c = cp*2;
    uint4 p0 = *reinterpret_cast<const uint4*>(vg + (size_t)c*L_ + g*8);
    uint4 p1 = *reinterpret_cast<const uint4*>(vg + (size_t)(c+1)*L_ + g*8);
    const u16* e0 = reinterpret_cast<const u16*>(&p0);
    const u16* e1 = reinterpret_cast<const u16*>(&p1);
    #pragma unroll
    for (int j = 0; j < 8; ++j){
      int p = g*8 + j;
      u32 packed = ((u32)e0[j]) | (((u32)e1[j]) << 16);
      *reinterpret_cast<u32*>(vtb + vt_off(p, c)) = packed;
    }
  }
  __syncthreads();

  const int w = tid >> 6, lane = tid & 63;
  const int fr = lane & 15, kq = (lane >> 4) * 8;
  const int prow = w*16;
  f32x4 acc[24];
  #pragma unroll
  for (int j = 0; j < 24; ++j) acc[j] = (f32x4){0.f,0.f,0.f,0.f};

  const u16* ab = attn96 + ((size_t)bb*NH)*DH*96;
  #pragma unroll
  for (int n = 0; n < NH; ++n){
    bf16x8 af[3];
    #pragma unroll
    for (int s = 0; s < 3; ++s){
      int ep = s*32 + kq;                       // e' in [0,96)
      int ch = n*DH + (ep >= 48 ? ep - 48 : ep);
      af[s] = *reinterpret_cast<const bf16x8*>(vtb + vt_off(prow + fr, ch));
    }
    #pragma unroll
    for (int jj = 0; jj < 3; ++jj){
      const u16* arow = ab + ((size_t)n*DH + jj*16 + fr)*96;
      #pragma unroll
      for (int s = 0; s < 3; ++s){
        bf16x8 bf = *reinterpret_cast<const bf16x8*>(arow + s*32 + kq);
        acc[n*3+jj] = __builtin_amdgcn_mfma_f32_16x16x32_bf16(af[s], bf, acc[n*3+jj], 0, 0, 0);
      }
    }
  }

  // fused LN2: per-pixel stats (pixel = row), fully intra-wave
  f32x4 s = {0.f,0.f,0.f,0.f}, s2 = {0.f,0.f,0.f,0.f};
  #pragma unroll
  for (int j = 0; j < 24; ++j){ s += acc[j]; s2 += acc[j]*acc[j]; }
  #pragma unroll
  for (int m = 1; m < 16; m <<= 1){
    #pragma unroll
    for (int r = 0; r < 4; ++r){
      s[r]  += __shfl_xor(s[r],  m);
      s2[r] += __shfl_xor(s2[r], m);
    }
  }
  f32x4 mu, rstd;
  #pragma unroll
  for (int r = 0; r < 4; ++r){
    mu[r]   = s[r] * (1.f/C_);
    rstd[r] = rsqrtf(s2[r]*(1.f/C_) - mu[r]*mu[r] + 1e-5f);
  }
  const int pbase = l0 + prow + (lane>>4)*4;
  #pragma unroll
  for (int j = 0; j < 24; ++j){
    int c = j*16 + fr;
    float wc = w2[c], bc = b2[c];
    f32x4 o;
    #pragma unroll
    for (int r = 0; r < 4; ++r)
      o[r] = (acc[j][r] - mu[r]) * rstd[r] * wc + bc;
    *reinterpret_cast<f32x4*>(out + ((size_t)bb*C_ + c)*L_ + pbase) = o;
  }
}

extern "C" void kernel_launch(void* const* d_in, const int* in_sizes, int n_in,
                              void* d_out, int out_size, void* d_ws, size_t ws_size,
                              hipStream_t stream){
  const float* x     = (const float*)d_in[0];
  const float* wq    = (const float*)d_in[1];
  const float* wk    = (const float*)d_in[2];
  const float* wv    = (const float*)d_in[3];
  const float* dwq   = (const float*)d_in[4];
  const float* dwk   = (const float*)d_in[5];
  const float* dwv   = (const float*)d_in[6];
  const float* scale = (const float*)d_in[7];
  const float* ln1w  = (const float*)d_in[8];
  const float* ln1b  = (const float*)d_in[9];
  const float* ln2w  = (const float*)d_in[10];
  const float* ln2b  = (const float*)d_in[11];
  float* out = (float*)d_out;

  char* ws = (char*)d_ws;
  u16*   qkv    = (u16*)ws;                          // [3][B][C][L] bf16  = 150,994,944 B
  u16*   xt     = (u16*)(ws + 150994944);            // [B*L][C] bf16     =  50,331,648 B
  u16*   wc     = (u16*)(ws + 201326592);            // [1152][384] bf16  =     884,736 B
  float* sumsq  = (float*)(ws + 202211328);          // [2][B*C] f32      =      12,288 B
  float* Spart  = (float*)(ws + 202223616);          // [8][32][2304] f32 =   2,359,296 B
  u16*   attn96 = (u16*)(ws + 204582912);            // [32][48][96] u16  =     294,912 B

  k_cvt_w  <<<1728, 256, 0, stream>>>(wq, wk, wv, wc);
  k_ln1    <<<256, 256, 0, stream>>>(x, ln1w, ln1b, xt);
  k_gemm   <<<9*512, 256, 0, stream>>>(wc, xt, qkv);
  k_dwconv <<<3*B_*C_, 256, 0, stream>>>(qkv, dwq, dwk, dwv, sumsq);
  k_qk     <<<SPLIT*B_*NH, 256, 0, stream>>>(qkv, Spart);
  k_softmax<<<B_*NH, 64, 0, stream>>>(Spart, sumsq, scale, attn96);
  k_av_ln2 <<<1024, 256, 0, stream>>>(qkv, attn96, ln2w, ln2b, out);
}

// Round 4
// 378.469 us; speedup vs baseline: 1.5602x; 1.2957x over previous
//
#include <hip/hip_runtime.h>
#include <hip/hip_bf16.h>
#include <stdint.h>

#define B_ 4
#define C_ 384
#define H_ 128
#define W_ 128
#define L_ (H_*W_)      // 16384
#define NH 8
#define DH 48           // C_/NH
#define SPLIT 8

typedef __attribute__((ext_vector_type(8))) short bf16x8;
typedef __attribute__((ext_vector_type(4))) float f32x4;
typedef unsigned short u16;
typedef unsigned int u32;

__device__ __forceinline__ float bf2f(u16 v){
  union { float f; u32 u; } x; x.u = ((u32)v) << 16; return x.f;
}
__device__ __forceinline__ u16 f2bf(float f){
  __hip_bfloat16 h = __float2bfloat16(f);
  return *reinterpret_cast<u16*>(&h);
}

#define GLOAD_LDS16(g, l) \
  __builtin_amdgcn_global_load_lds((const __attribute__((address_space(1))) u32*)(g), \
                                   (__attribute__((address_space(3))) u32*)(l), 16, 0, 0)

// ---------------- K0: convert 1x1 conv weights to bf16, concat [1152][384] ----------------
__global__ __launch_bounds__(256) void k_cvt_w(const float* __restrict__ wq,
                                               const float* __restrict__ wk,
                                               const float* __restrict__ wv,
                                               u16* __restrict__ wc){
  int i = blockIdx.x * 256 + threadIdx.x;
  if (i >= 3*C_*C_) return;
  int m = i / C_;
  int c = i - m*C_;
  const float* src = (m < C_) ? wq : (m < 2*C_) ? wk : wv;
  int mm = (m >= 2*C_) ? m - 2*C_ : (m >= C_) ? m - C_ : m;
  wc[i] = f2bf(src[mm*C_ + c]);
}

// ---------------- K1: LayerNorm over C, write transposed bf16 [B*L][C] ----------------
// Block: 64 pixels x 384 channels. 256 thr = 16 pixel-groups (4 px, float4) x 16 ch-groups (24 ch).
// x values held in registers (no 2nd global pass); stats reduced intra-wave via shfl_xor over cg.
__global__ __launch_bounds__(256) void k_ln1(const float* __restrict__ x,
                                             const float* __restrict__ w,
                                             const float* __restrict__ b,
                                             u16* __restrict__ xt){
  const int tid = threadIdx.x;
  const int bb = blockIdx.x >> 8;          // 256 blocks per batch
  const int l0 = (blockIdx.x & 255) << 6;  // 64-pixel tile
  const int pg = tid >> 4;                 // 0..15, pixels pg*4..pg*4+3
  const int cg = tid & 15;                 // 0..15, channels cg*24..cg*24+23
  const int c0 = cg * 24;
  const float* xp = x + (size_t)bb*C_*L_ + (size_t)c0*L_ + l0 + pg*4;

  f32x4 vals[24];
  #pragma unroll
  for (int ci = 0; ci < 24; ++ci)
    vals[ci] = *reinterpret_cast<const f32x4*>(xp + (size_t)ci*L_);

  f32x4 s = {0.f,0.f,0.f,0.f}, s2 = {0.f,0.f,0.f,0.f};
  #pragma unroll
  for (int ci = 0; ci < 24; ++ci){ s += vals[ci]; s2 += vals[ci]*vals[ci]; }
  #pragma unroll
  for (int m = 1; m < 16; m <<= 1){
    #pragma unroll
    for (int r = 0; r < 4; ++r){
      s[r]  += __shfl_xor(s[r],  m);
      s2[r] += __shfl_xor(s2[r], m);
    }
  }
  f32x4 mu, rstd;
  #pragma unroll
  for (int r = 0; r < 4; ++r){
    mu[r]   = s[r] * (1.f/C_);
    rstd[r] = rsqrtf(s2[r]*(1.f/C_) - mu[r]*mu[r] + 1e-5f);
  }

  u16* dst = xt + ((size_t)bb*L_ + l0 + pg*4)*C_ + c0;
  #pragma unroll
  for (int j = 0; j < 3; ++j){
    f32x4 w0 = *reinterpret_cast<const f32x4*>(w + c0 + j*8);
    f32x4 w1 = *reinterpret_cast<const f32x4*>(w + c0 + j*8 + 4);
    f32x4 b0 = *reinterpret_cast<const f32x4*>(b + c0 + j*8);
    f32x4 b1 = *reinterpret_cast<const f32x4*>(b + c0 + j*8 + 4);
    #pragma unroll
    for (int pp = 0; pp < 4; ++pp){
      uint4 pk;
      u16* tp = reinterpret_cast<u16*>(&pk);
      #pragma unroll
      for (int e = 0; e < 4; ++e)
        tp[e]   = f2bf((vals[j*8+e][pp]   - mu[pp]) * rstd[pp] * w0[e] + b0[e]);
      #pragma unroll
      for (int e = 0; e < 4; ++e)
        tp[4+e] = f2bf((vals[j*8+4+e][pp] - mu[pp]) * rstd[pp] * w1[e] + b1[e]);
      *reinterpret_cast<uint4*>(dst + (size_t)pp*C_ + j*8) = pk;
    }
  }
}

// ---------------- K2: GEMM qkv = Wc[1152x384] * xt^T -> [3][B][C][L] bf16 ----------------
__global__ __launch_bounds__(256) void k_gemm(const u16* __restrict__ Wc,
                                              const u16* __restrict__ Xt,
                                              u16* __restrict__ qkv){
  __shared__ u16 As[128*32];
  __shared__ u16 Bs[128*32];
  const int tid = threadIdx.x;
  const int bm = blockIdx.x % 9;
  const int bn = blockIdx.x / 9;
  const int m0 = bm * 128;
  const int n0 = bn * 128;
  const int w = tid >> 6, lane = tid & 63;
  const int wm = (w >> 1) * 64, wn = (w & 1) * 64;
  const int fr = lane & 15, kq = (lane >> 4) * 8;

  f32x4 acc[4][4] = {};

  for (int k0 = 0; k0 < 384; k0 += 32){
    #pragma unroll
    for (int i = 0; i < 2; ++i){
      int idx = i*256 + tid;          // 0..511, 16B each
      int row = idx >> 2, q = idx & 3;
      GLOAD_LDS16(Wc + (size_t)(m0+row)*384 + k0 + q*8, As + idx*8);
      GLOAD_LDS16(Xt + (size_t)(n0+row)*384 + k0 + q*8, Bs + idx*8);
    }
    __syncthreads();
    bf16x8 af[4], bfm[4];
    #pragma unroll
    for (int i = 0; i < 4; ++i)
      af[i] = *reinterpret_cast<const bf16x8*>(As + (wm + i*16 + fr)*32 + kq);
    #pragma unroll
    for (int j = 0; j < 4; ++j)
      bfm[j] = *reinterpret_cast<const bf16x8*>(Bs + (wn + j*16 + fr)*32 + kq);
    #pragma unroll
    for (int i = 0; i < 4; ++i)
      #pragma unroll
      for (int j = 0; j < 4; ++j)
        acc[i][j] = __builtin_amdgcn_mfma_f32_16x16x32_bf16(af[i], bfm[j], acc[i][j], 0, 0, 0);
    __syncthreads();
  }

  #pragma unroll
  for (int i = 0; i < 4; ++i){
    int mbase = m0 + wm + i*16 + (lane >> 4) * 4;
    #pragma unroll
    for (int j = 0; j < 4; ++j){
      int n = n0 + wn + j*16 + fr;
      int bb = n >> 14, l = n & (L_-1);
      #pragma unroll
      for (int r = 0; r < 4; ++r){
        int m = mbase + r;
        int proj = (m >= 2*C_) ? 2 : (m >= C_) ? 1 : 0;
        int c = m - proj*C_;
        qkv[(((size_t)proj*B_ + bb)*C_ + c)*L_ + l] = f2bf(acc[i][j][r]);
      }
    }
  }
}

// ---------------- K3: depthwise 3x3 in-place + per-channel sumsq for q,k ----------------
__global__ __launch_bounds__(256) void k_dwconv(u16* __restrict__ qkv,
                                                const float* __restrict__ dwq,
                                                const float* __restrict__ dwk,
                                                const float* __restrict__ dwv,
                                                float* __restrict__ sumsq){
  __shared__ u16 pl[128*128];
  int pid = blockIdx.x;                  // t*B*C + b*C + c
  int t = pid / (B_*C_);
  int bc = pid - t*(B_*C_);
  int c = bc % C_;
  const float* dw = ((t == 0) ? dwq : (t == 1) ? dwk : dwv) + c*9;
  u16* plane = qkv + ((size_t)t*B_*C_ + bc) * L_;
  int tid = threadIdx.x;
  #pragma unroll
  for (int i = 0; i < 8; ++i){
    int idx = i*256 + tid;
    *reinterpret_cast<uint4*>(pl + idx*8) = *reinterpret_cast<const uint4*>(plane + idx*8);
  }
  float wgt[9];
  #pragma unroll
  for (int i = 0; i < 9; ++i) wgt[i] = dw[i];
  __syncthreads();
  float ss = 0.f;
  for (int p = 0; p < 64; ++p){
    int pix = p*256 + tid;
    int y = pix >> 7, xx0 = pix & 127;
    float a = 0.f;
    #pragma unroll
    for (int dy = -1; dy <= 1; ++dy){
      int yy = y + dy;
      if (yy < 0 || yy > 127) continue;
      #pragma unroll
      for (int dx = -1; dx <= 1; ++dx){
        int xx = xx0 + dx;
        if (xx < 0 || xx > 127) continue;
        a += wgt[(dy+1)*3 + (dx+1)] * bf2f(pl[yy*128 + xx]);
      }
    }
    plane[pix] = f2bf(a);
    ss += a * a;
  }
  if (t < 2){
    #pragma unroll
    for (int off = 32; off > 0; off >>= 1) ss += __shfl_down(ss, off);
    __shared__ float red[4];
    if ((tid & 63) == 0) red[tid >> 6] = ss;
    __syncthreads();
    if (tid == 0) sumsq[t*(B_*C_) + bc] = red[0] + red[1] + red[2] + red[3];
  }
}

// ---------------- K4: attention logits (split-K over L), S_part[s][b][n][48][48] ----------------
__global__ __launch_bounds__(256) void k_qk(const u16* __restrict__ qkv,
                                            float* __restrict__ Spart){
  int gid = blockIdx.x;                 // (s*B + b)*NH + n
  int s = gid / (B_*NH);
  int bn = gid - s*(B_*NH);
  int b = bn / NH, n = bn - b*NH;
  const u16* qb = qkv + ((size_t)b*C_ + n*DH) * L_;
  const u16* kb = qkv + ((size_t)B_*C_ + (size_t)b*C_ + n*DH) * L_;
  int tid = threadIdx.x, w = tid >> 6, lane = tid & 63;
  int fr = lane & 15, kq = (lane >> 4) * 8;
  int l0 = s * (L_/SPLIT) + w * (L_/SPLIT/4);     // 2048/block, 512/wave
  f32x4 acc[3][3] = {};
  for (int kk = 0; kk < 512; kk += 32){
    int koff = l0 + kk + kq;
    bf16x8 af[3], bfm[3];
    #pragma unroll
    for (int i = 0; i < 3; ++i) af[i]  = *reinterpret_cast<const bf16x8*>(qb + (size_t)(i*16+fr)*L_ + koff);
    #pragma unroll
    for (int j = 0; j < 3; ++j) bfm[j] = *reinterpret_cast<const bf16x8*>(kb + (size_t)(j*16+fr)*L_ + koff);
    #pragma unroll
    for (int i = 0; i < 3; ++i)
      #pragma unroll
      for (int j = 0; j < 3; ++j)
        acc[i][j] = __builtin_amdgcn_mfma_f32_16x16x32_bf16(af[i], bfm[j], acc[i][j], 0, 0, 0);
  }
  __shared__ float red[48*48];
  for (int ww = 0; ww < 4; ++ww){
    if (w == ww){
      #pragma unroll
      for (int i = 0; i < 3; ++i)
        #pragma unroll
        for (int j = 0; j < 3; ++j)
          #pragma unroll
          for (int r = 0; r < 4; ++r){
            int row = i*16 + (lane >> 4)*4 + r;
            int col = j*16 + fr;
            if (ww == 0) red[row*48 + col] = acc[i][j][r];
            else         red[row*48 + col] += acc[i][j][r];
          }
    }
    __syncthreads();
  }
  float* dst = Spart + ((size_t)gid) * 2304;
  for (int idx = tid; idx < 2304; idx += 256) dst[idx] = red[idx];
}

// ---------------- K5: reduce split-K, fold L2 norms + scale, softmax -> bf16 hi|lo [d][96] ----------------
__global__ void k_softmax(const float* __restrict__ Spart,
                          const float* __restrict__ sumsq,
                          const float* __restrict__ scale,
                          u16* __restrict__ attn96){
  int bn = blockIdx.x;                  // b*NH + n
  int b = bn / NH, n = bn - b*NH;
  int i = threadIdx.x;
  if (i >= DH) return;
  const float* sq = sumsq + (size_t)b*C_ + n*DH;
  const float* sk = sumsq + (size_t)B_*C_ + (size_t)b*C_ + n*DH;
  float nq = fmaxf(sqrtf(sq[i]), 1e-12f);
  float sc = scale[n];
  float row[48];
  #pragma unroll
  for (int j = 0; j < DH; ++j){
    float acc = 0.f;
    #pragma unroll
    for (int s = 0; s < SPLIT; ++s)
      acc += Spart[((size_t)(s*(B_*NH) + bn))*2304 + i*48 + j];
    float nk = fmaxf(sqrtf(sk[j]), 1e-12f);
    row[j] = acc / (nq * nk) * sc;
  }
  float m = row[0];
  #pragma unroll
  for (int j = 1; j < DH; ++j) m = fmaxf(m, row[j]);
  float sum = 0.f;
  #pragma unroll
  for (int j = 0; j < DH; ++j){ row[j] = __expf(row[j] - m); sum += row[j]; }
  float inv = 1.f / sum;
  u16* dst = attn96 + ((size_t)bn)*DH*96 + i*96;     // row d=i: hi[0..48) | lo[48..96)
  #pragma unroll
  for (int j = 0; j < DH; ++j){
    float a = row[j] * inv;
    u16 hi = f2bf(a);
    float lo = a - bf2f(hi);
    dst[j]      = hi;
    dst[48 + j] = f2bf(lo);
  }
}

// ---------------- K6: out = attn @ v via MFMA (hi+lo split-K=96), fused LayerNorm ----------------
#define VT_STRIDE 784
__device__ __forceinline__ int vt_off(int p, int ch){
  return p*VT_STRIDE + ((p>>3)<<4) + 2*ch;
}
__global__ __launch_bounds__(256) void k_av_ln2(const u16* __restrict__ qkv,
                                                const u16* __restrict__ attn96,
                                                const float* __restrict__ w2,
                                                const float* __restrict__ b2,
                                                float* __restrict__ out){
  __shared__ u16 vt[(64*VT_STRIDE + 8*16)/2];     // 50304 B
  char* vtb = reinterpret_cast<char*>(vt);
  const int tid = threadIdx.x;
  const int bb = blockIdx.x >> 8;        // 256 tiles per batch
  const int l0 = (blockIdx.x & 255) << 6;
  const u16* vg = qkv + ((size_t)2*B_*C_ + (size_t)bb*C_)*L_ + l0;

  // stage v[c][l0..l0+63] -> vt[p][c] (transposed): channel-pairs, u32 writes
  #pragma unroll
  for (int it = 0; it < 6; ++it){
    int idx = it*256 + tid;            // 0..1535
    int cp = idx >> 3, g = idx & 7;    // cp: channel pair 0..191, g: pixel group
    int c = cp*2;
    uint4 p0 = *reinterpret_cast<const uint4*>(vg + (size_t)c*L_ + g*8);
    uint4 p1 = *reinterpret_cast<const uint4*>(vg + (size_t)(c+1)*L_ + g*8);
    const u16* e0 = reinterpret_cast<const u16*>(&p0);
    const u16* e1 = reinterpret_cast<const u16*>(&p1);
    #pragma unroll
    for (int j = 0; j < 8; ++j){
      int p = g*8 + j;
      u32 packed = ((u32)e0[j]) | (((u32)e1[j]) << 16);
      *reinterpret_cast<u32*>(vtb + vt_off(p, c)) = packed;
    }
  }
  __syncthreads();

  const int w = tid >> 6, lane = tid & 63;
  const int fr = lane & 15, kq = (lane >> 4) * 8;
  const int prow = w*16;
  f32x4 acc[24];
  #pragma unroll
  for (int j = 0; j < 24; ++j) acc[j] = (f32x4){0.f,0.f,0.f,0.f};

  const u16* ab = attn96 + ((size_t)bb*NH)*DH*96;
  #pragma unroll
  for (int n = 0; n < NH; ++n){
    bf16x8 af[3];
    #pragma unroll
    for (int s = 0; s < 3; ++s){
      int ep = s*32 + kq;                       // e' in [0,96)
      int ch = n*DH + (ep >= 48 ? ep - 48 : ep);
      af[s] = *reinterpret_cast<const bf16x8*>(vtb + vt_off(prow + fr, ch));
    }
    #pragma unroll
    for (int jj = 0; jj < 3; ++jj){
      const u16* arow = ab + ((size_t)n*DH + jj*16 + fr)*96;
      #pragma unroll
      for (int s = 0; s < 3; ++s){
        bf16x8 bf = *reinterpret_cast<const bf16x8*>(arow + s*32 + kq);
        acc[n*3+jj] = __builtin_amdgcn_mfma_f32_16x16x32_bf16(af[s], bf, acc[n*3+jj], 0, 0, 0);
      }
    }
  }

  // fused LN2: per-pixel stats (pixel = row), fully intra-wave
  f32x4 s = {0.f,0.f,0.f,0.f}, s2 = {0.f,0.f,0.f,0.f};
  #pragma unroll
  for (int j = 0; j < 24; ++j){ s += acc[j]; s2 += acc[j]*acc[j]; }
  #pragma unroll
  for (int m = 1; m < 16; m <<= 1){
    #pragma unroll
    for (int r = 0; r < 4; ++r){
      s[r]  += __shfl_xor(s[r],  m);
      s2[r] += __shfl_xor(s2[r], m);
    }
  }
  f32x4 mu, rstd;
  #pragma unroll
  for (int r = 0; r < 4; ++r){
    mu[r]   = s[r] * (1.f/C_);
    rstd[r] = rsqrtf(s2[r]*(1.f/C_) - mu[r]*mu[r] + 1e-5f);
  }
  const int pbase = l0 + prow + (lane>>4)*4;
  #pragma unroll
  for (int j = 0; j < 24; ++j){
    int c = j*16 + fr;
    float wc = w2[c], bc = b2[c];
    f32x4 o;
    #pragma unroll
    for (int r = 0; r < 4; ++r)
      o[r] = (acc[j][r] - mu[r]) * rstd[r] * wc + bc;
    *reinterpret_cast<f32x4*>(out + ((size_t)bb*C_ + c)*L_ + pbase) = o;
  }
}

extern "C" void kernel_launch(void* const* d_in, const int* in_sizes, int n_in,
                              void* d_out, int out_size, void* d_ws, size_t ws_size,
                              hipStream_t stream){
  const float* x     = (const float*)d_in[0];
  const float* wq    = (const float*)d_in[1];
  const float* wk    = (const float*)d_in[2];
  const float* wv    = (const float*)d_in[3];
  const float* dwq   = (const float*)d_in[4];
  const float* dwk   = (const float*)d_in[5];
  const float* dwv   = (const float*)d_in[6];
  const float* scale = (const float*)d_in[7];
  const float* ln1w  = (const float*)d_in[8];
  const float* ln1b  = (const float*)d_in[9];
  const float* ln2w  = (const float*)d_in[10];
  const float* ln2b  = (const float*)d_in[11];
  float* out = (float*)d_out;

  char* ws = (char*)d_ws;
  u16*   qkv    = (u16*)ws;                          // [3][B][C][L] bf16  = 150,994,944 B
  u16*   xt     = (u16*)(ws + 150994944);            // [B*L][C] bf16     =  50,331,648 B
  u16*   wc     = (u16*)(ws + 201326592);            // [1152][384] bf16  =     884,736 B
  float* sumsq  = (float*)(ws + 202211328);          // [2][B*C] f32      =      12,288 B
  float* Spart  = (float*)(ws + 202223616);          // [8][32][2304] f32 =   2,359,296 B
  u16*   attn96 = (u16*)(ws + 204582912);            // [32][48][96] u16  =     294,912 B

  k_cvt_w  <<<1728, 256, 0, stream>>>(wq, wk, wv, wc);
  k_ln1    <<<1024, 256, 0, stream>>>(x, ln1w, ln1b, xt);
  k_gemm   <<<9*512, 256, 0, stream>>>(wc, xt, qkv);
  k_dwconv <<<3*B_*C_, 256, 0, stream>>>(qkv, dwq, dwk, dwv, sumsq);
  k_qk     <<<SPLIT*B_*NH, 256, 0, stream>>>(qkv, Spart);
  k_softmax<<<B_*NH, 64, 0, stream>>>(Spart, sumsq, scale, attn96);
  k_av_ln2 <<<1024, 256, 0, stream>>>(qkv, attn96, ln2w, ln2b, out);
}

// Round 5
// 291.840 us; speedup vs baseline: 2.0233x; 1.2968x over previous
//
#include <hip/hip_runtime.h>
#include <hip/hip_bf16.h>
#include <stdint.h>

#define B_ 4
#define C_ 384
#define H_ 128
#define W_ 128
#define L_ (H_*W_)      // 16384
#define NH 8
#define DH 48           // C_/NH
#define SPLIT 8

typedef __attribute__((ext_vector_type(8))) short bf16x8;
typedef __attribute__((ext_vector_type(4))) float f32x4;
typedef unsigned short u16;
typedef unsigned int u32;

__device__ __forceinline__ float bf2f(u16 v){
  union { float f; u32 u; } x; x.u = ((u32)v) << 16; return x.f;
}
__device__ __forceinline__ u16 f2bf(float f){
  __hip_bfloat16 h = __float2bfloat16(f);
  return *reinterpret_cast<u16*>(&h);
}

#define GLOAD_LDS16(g, l) \
  __builtin_amdgcn_global_load_lds((const __attribute__((address_space(1))) u32*)(g), \
                                   (__attribute__((address_space(3))) u32*)(l), 16, 0, 0)

// ---------------- K0: convert 1x1 conv weights to bf16, concat [1152][384] ----------------
__global__ __launch_bounds__(256) void k_cvt_w(const float* __restrict__ wq,
                                               const float* __restrict__ wk,
                                               const float* __restrict__ wv,
                                               u16* __restrict__ wc){
  int i = blockIdx.x * 256 + threadIdx.x;
  if (i >= 3*C_*C_) return;
  int m = i / C_;
  int c = i - m*C_;
  const float* src = (m < C_) ? wq : (m < 2*C_) ? wk : wv;
  int mm = (m >= 2*C_) ? m - 2*C_ : (m >= C_) ? m - C_ : m;
  wc[i] = f2bf(src[mm*C_ + c]);
}

// ---------------- K1: LayerNorm over C, write transposed bf16 [B*L][C] ----------------
__global__ __launch_bounds__(256) void k_ln1(const float* __restrict__ x,
                                             const float* __restrict__ w,
                                             const float* __restrict__ b,
                                             u16* __restrict__ xt){
  const int tid = threadIdx.x;
  const int bb = blockIdx.x >> 8;          // 256 blocks per batch
  const int l0 = (blockIdx.x & 255) << 6;  // 64-pixel tile
  const int pg = tid >> 4;                 // 0..15, pixels pg*4..pg*4+3
  const int cg = tid & 15;                 // 0..15, channels cg*24..cg*24+23
  const int c0 = cg * 24;
  const float* xp = x + (size_t)bb*C_*L_ + (size_t)c0*L_ + l0 + pg*4;

  f32x4 vals[24];
  #pragma unroll
  for (int ci = 0; ci < 24; ++ci)
    vals[ci] = *reinterpret_cast<const f32x4*>(xp + (size_t)ci*L_);

  f32x4 s = {0.f,0.f,0.f,0.f}, s2 = {0.f,0.f,0.f,0.f};
  #pragma unroll
  for (int ci = 0; ci < 24; ++ci){ s += vals[ci]; s2 += vals[ci]*vals[ci]; }
  #pragma unroll
  for (int m = 1; m < 16; m <<= 1){
    #pragma unroll
    for (int r = 0; r < 4; ++r){
      s[r]  += __shfl_xor(s[r],  m);
      s2[r] += __shfl_xor(s2[r], m);
    }
  }
  f32x4 mu, rstd;
  #pragma unroll
  for (int r = 0; r < 4; ++r){
    mu[r]   = s[r] * (1.f/C_);
    rstd[r] = rsqrtf(s2[r]*(1.f/C_) - mu[r]*mu[r] + 1e-5f);
  }

  u16* dst = xt + ((size_t)bb*L_ + l0 + pg*4)*C_ + c0;
  #pragma unroll
  for (int j = 0; j < 3; ++j){
    f32x4 w0 = *reinterpret_cast<const f32x4*>(w + c0 + j*8);
    f32x4 w1 = *reinterpret_cast<const f32x4*>(w + c0 + j*8 + 4);
    f32x4 b0 = *reinterpret_cast<const f32x4*>(b + c0 + j*8);
    f32x4 b1 = *reinterpret_cast<const f32x4*>(b + c0 + j*8 + 4);
    #pragma unroll
    for (int pp = 0; pp < 4; ++pp){
      uint4 pk;
      u16* tp = reinterpret_cast<u16*>(&pk);
      #pragma unroll
      for (int e = 0; e < 4; ++e)
        tp[e]   = f2bf((vals[j*8+e][pp]   - mu[pp]) * rstd[pp] * w0[e] + b0[e]);
      #pragma unroll
      for (int e = 0; e < 4; ++e)
        tp[4+e] = f2bf((vals[j*8+4+e][pp] - mu[pp]) * rstd[pp] * w1[e] + b1[e]);
      *reinterpret_cast<uint4*>(dst + (size_t)pp*C_ + j*8) = pk;
    }
  }
}

// ---------------- K2: GEMM qkv = Wc[1152x384] * xt^T -> [3][B][C][L] bf16 ----------------
__global__ __launch_bounds__(256) void k_gemm(const u16* __restrict__ Wc,
                                              const u16* __restrict__ Xt,
                                              u16* __restrict__ qkv){
  __shared__ u16 As[128*32];
  __shared__ u16 Bs[128*32];
  const int tid = threadIdx.x;
  const int bm = blockIdx.x % 9;
  const int bn = blockIdx.x / 9;
  const int m0 = bm * 128;
  const int n0 = bn * 128;
  const int w = tid >> 6, lane = tid & 63;
  const int wm = (w >> 1) * 64, wn = (w & 1) * 64;
  const int fr = lane & 15, kq = (lane >> 4) * 8;

  f32x4 acc[4][4] = {};

  for (int k0 = 0; k0 < 384; k0 += 32){
    #pragma unroll
    for (int i = 0; i < 2; ++i){
      int idx = i*256 + tid;          // 0..511, 16B each
      int row = idx >> 2, q = idx & 3;
      GLOAD_LDS16(Wc + (size_t)(m0+row)*384 + k0 + q*8, As + idx*8);
      GLOAD_LDS16(Xt + (size_t)(n0+row)*384 + k0 + q*8, Bs + idx*8);
    }
    __syncthreads();
    bf16x8 af[4], bfm[4];
    #pragma unroll
    for (int i = 0; i < 4; ++i)
      af[i] = *reinterpret_cast<const bf16x8*>(As + (wm + i*16 + fr)*32 + kq);
    #pragma unroll
    for (int j = 0; j < 4; ++j)
      bfm[j] = *reinterpret_cast<const bf16x8*>(Bs + (wn + j*16 + fr)*32 + kq);
    #pragma unroll
    for (int i = 0; i < 4; ++i)
      #pragma unroll
      for (int j = 0; j < 4; ++j)
        acc[i][j] = __builtin_amdgcn_mfma_f32_16x16x32_bf16(af[i], bfm[j], acc[i][j], 0, 0, 0);
    __syncthreads();
  }

  #pragma unroll
  for (int i = 0; i < 4; ++i){
    int mbase = m0 + wm + i*16 + (lane >> 4) * 4;
    #pragma unroll
    for (int j = 0; j < 4; ++j){
      int n = n0 + wn + j*16 + fr;
      int bb = n >> 14, l = n & (L_-1);
      #pragma unroll
      for (int r = 0; r < 4; ++r){
        int m = mbase + r;
        int proj = (m >= 2*C_) ? 2 : (m >= C_) ? 1 : 0;
        int c = m - proj*C_;
        qkv[(((size_t)proj*B_ + bb)*C_ + c)*L_ + l] = f2bf(acc[i][j][r]);
      }
    }
  }
}

// ---------------- K3: depthwise 3x3 in-place + per-channel sumsq for q,k ----------------
// Compute phase re-tiled: each thread owns an 8x8 pixel tile; per input row one
// ds_read_b128 (8 px) + halo via __shfl from neighbor lanes; rolling 3-row window.
__global__ __launch_bounds__(256) void k_dwconv(u16* __restrict__ qkv,
                                                const float* __restrict__ dwq,
                                                const float* __restrict__ dwk,
                                                const float* __restrict__ dwv,
                                                float* __restrict__ sumsq){
  __shared__ u16 pl[128*128];
  int pid = blockIdx.x;                  // t*B*C + b*C + c
  int t = pid / (B_*C_);
  int bc = pid - t*(B_*C_);
  int c = bc % C_;
  const float* dw = ((t == 0) ? dwq : (t == 1) ? dwk : dwv) + c*9;
  u16* plane = qkv + ((size_t)t*B_*C_ + bc) * L_;
  int tid = threadIdx.x;
  #pragma unroll
  for (int i = 0; i < 8; ++i){
    int idx = i*256 + tid;
    *reinterpret_cast<uint4*>(pl + idx*8) = *reinterpret_cast<const uint4*>(plane + idx*8);
  }
  float wgt[9];
  #pragma unroll
  for (int i = 0; i < 9; ++i) wgt[i] = dw[i];
  __syncthreads();

  const int tx = tid & 15;           // tile col: pixels tx*8..tx*8+7
  const int ty = tid >> 4;           // tile row: rows ty*8..ty*8+7
  const int lane = tid & 63;
  const int y0 = ty*8;

  float rv[3][8], rl[3], rr_[3];
  float ss = 0.f;

  // rolling over 10 input rows y0-1 .. y0+8; slot = i%3 (fully unrolled -> static)
  #pragma unroll
  for (int i = 0; i < 10; ++i){
    const int sl = i % 3;
    int r = y0 - 1 + i;
    int rc = (r < 0) ? 0 : (r > 127 ? 127 : r);
    uint4 pk = *reinterpret_cast<const uint4*>(pl + rc*128 + tx*8);
    const u16* e = reinterpret_cast<const u16*>(&pk);
    bool oob = (r < 0) || (r > 127);
    #pragma unroll
    for (int k = 0; k < 8; ++k)
      rv[sl][k] = oob ? 0.f : bf2f(e[k]);
    float lft = __shfl(rv[sl][7], lane - 1);
    float rgt = __shfl(rv[sl][0], lane + 1);
    rl[sl]  = (tx == 0)  ? 0.f : lft;
    rr_[sl] = (tx == 15) ? 0.f : rgt;

    if (i >= 2){
      const int sa = (i-2) % 3, sb = (i-1) % 3, sc = i % 3;
      const int y = i - 2;
      float o[8];
      #pragma unroll
      for (int xx = 0; xx < 8; ++xx){
        float am1 = (xx == 0) ? rl[sa]  : rv[sa][xx-1];
        float ap1 = (xx == 7) ? rr_[sa] : rv[sa][xx+1];
        float bm1 = (xx == 0) ? rl[sb]  : rv[sb][xx-1];
        float bp1 = (xx == 7) ? rr_[sb] : rv[sb][xx+1];
        float cm1 = (xx == 0) ? rl[sc]  : rv[sc][xx-1];
        float cp1 = (xx == 7) ? rr_[sc] : rv[sc][xx+1];
        float a = wgt[0]*am1 + wgt[1]*rv[sa][xx] + wgt[2]*ap1
                + wgt[3]*bm1 + wgt[4]*rv[sb][xx] + wgt[5]*bp1
                + wgt[6]*cm1 + wgt[7]*rv[sc][xx] + wgt[8]*cp1;
        o[xx] = a;
        ss += a * a;
      }
      uint4 st;
      u16* sp = reinterpret_cast<u16*>(&st);
      #pragma unroll
      for (int xx = 0; xx < 8; ++xx) sp[xx] = f2bf(o[xx]);
      *reinterpret_cast<uint4*>(plane + (y0 + y)*128 + tx*8) = st;
    }
  }

  if (t < 2){
    #pragma unroll
    for (int off = 32; off > 0; off >>= 1) ss += __shfl_down(ss, off);
    __shared__ float red[4];
    if ((tid & 63) == 0) red[tid >> 6] = ss;
    __syncthreads();
    if (tid == 0) sumsq[t*(B_*C_) + bc] = red[0] + red[1] + red[2] + red[3];
  }
}

// ---------------- K4: attention logits (split-K over L), S_part[s][b][n][48][48] ----------------
__global__ __launch_bounds__(256) void k_qk(const u16* __restrict__ qkv,
                                            float* __restrict__ Spart){
  int gid = blockIdx.x;                 // (s*B + b)*NH + n
  int s = gid / (B_*NH);
  int bn = gid - s*(B_*NH);
  int b = bn / NH, n = bn - b*NH;
  const u16* qb = qkv + ((size_t)b*C_ + n*DH) * L_;
  const u16* kb = qkv + ((size_t)B_*C_ + (size_t)b*C_ + n*DH) * L_;
  int tid = threadIdx.x, w = tid >> 6, lane = tid & 63;
  int fr = lane & 15, kq = (lane >> 4) * 8;
  int l0 = s * (L_/SPLIT) + w * (L_/SPLIT/4);     // 2048/block, 512/wave
  f32x4 acc[3][3] = {};
  for (int kk = 0; kk < 512; kk += 32){
    int koff = l0 + kk + kq;
    bf16x8 af[3], bfm[3];
    #pragma unroll
    for (int i = 0; i < 3; ++i) af[i]  = *reinterpret_cast<const bf16x8*>(qb + (size_t)(i*16+fr)*L_ + koff);
    #pragma unroll
    for (int j = 0; j < 3; ++j) bfm[j] = *reinterpret_cast<const bf16x8*>(kb + (size_t)(j*16+fr)*L_ + koff);
    #pragma unroll
    for (int i = 0; i < 3; ++i)
      #pragma unroll
      for (int j = 0; j < 3; ++j)
        acc[i][j] = __builtin_amdgcn_mfma_f32_16x16x32_bf16(af[i], bfm[j], acc[i][j], 0, 0, 0);
  }
  __shared__ float red[48*48];
  for (int ww = 0; ww < 4; ++ww){
    if (w == ww){
      #pragma unroll
      for (int i = 0; i < 3; ++i)
        #pragma unroll
        for (int j = 0; j < 3; ++j)
          #pragma unroll
          for (int r = 0; r < 4; ++r){
            int row = i*16 + (lane >> 4)*4 + r;
            int col = j*16 + fr;
            if (ww == 0) red[row*48 + col] = acc[i][j][r];
            else         red[row*48 + col] += acc[i][j][r];
          }
    }
    __syncthreads();
  }
  float* dst = Spart + ((size_t)gid) * 2304;
  for (int idx = tid; idx < 2304; idx += 256) dst[idx] = red[idx];
}

// ---------------- K5: reduce split-K, fold L2 norms + scale, softmax -> bf16 hi|lo [d][96] ----------------
__global__ void k_softmax(const float* __restrict__ Spart,
                          const float* __restrict__ sumsq,
                          const float* __restrict__ scale,
                          u16* __restrict__ attn96){
  int bn = blockIdx.x;                  // b*NH + n
  int b = bn / NH, n = bn - b*NH;
  int i = threadIdx.x;
  if (i >= DH) return;
  const float* sq = sumsq + (size_t)b*C_ + n*DH;
  const float* sk = sumsq + (size_t)B_*C_ + (size_t)b*C_ + n*DH;
  float nq = fmaxf(sqrtf(sq[i]), 1e-12f);
  float sc = scale[n];
  float row[48];
  #pragma unroll
  for (int j = 0; j < DH; ++j){
    float acc = 0.f;
    #pragma unroll
    for (int s = 0; s < SPLIT; ++s)
      acc += Spart[((size_t)(s*(B_*NH) + bn))*2304 + i*48 + j];
    float nk = fmaxf(sqrtf(sk[j]), 1e-12f);
    row[j] = acc / (nq * nk) * sc;
  }
  float m = row[0];
  #pragma unroll
  for (int j = 1; j < DH; ++j) m = fmaxf(m, row[j]);
  float sum = 0.f;
  #pragma unroll
  for (int j = 0; j < DH; ++j){ row[j] = __expf(row[j] - m); sum += row[j]; }
  float inv = 1.f / sum;
  u16* dst = attn96 + ((size_t)bn)*DH*96 + i*96;     // row d=i: hi[0..48) | lo[48..96)
  #pragma unroll
  for (int j = 0; j < DH; ++j){
    float a = row[j] * inv;
    u16 hi = f2bf(a);
    float lo = a - bf2f(hi);
    dst[j]      = hi;
    dst[48 + j] = f2bf(lo);
  }
}

// ---------------- K6: out = attn @ v via MFMA (hi+lo split-K=96), fused LayerNorm ----------------
#define VT_STRIDE 784
__device__ __forceinline__ int vt_off(int p, int ch){
  return p*VT_STRIDE + ((p>>3)<<4) + 2*ch;
}
__global__ __launch_bounds__(256) void k_av_ln2(const u16* __restrict__ qkv,
                                                const u16* __restrict__ attn96,
                                                const float* __restrict__ w2,
                                                const float* __restrict__ b2,
                                                float* __restrict__ out){
  __shared__ u16 vt[(64*VT_STRIDE + 8*16)/2];     // 50304 B
  char* vtb = reinterpret_cast<char*>(vt);
  const int tid = threadIdx.x;
  const int bb = blockIdx.x >> 8;        // 256 tiles per batch
  const int l0 = (blockIdx.x & 255) << 6;
  const u16* vg = qkv + ((size_t)2*B_*C_ + (size_t)bb*C_)*L_ + l0;

  // stage v[c][l0..l0+63] -> vt[p][c] (transposed): channel-pairs, u32 writes
  #pragma unroll
  for (int it = 0; it < 6; ++it){
    int idx = it*256 + tid;            // 0..1535
    int cp = idx >> 3, g = idx & 7;    // cp: channel pair 0..191, g: pixel group
    int c = cp*2;
    uint4 p0 = *reinterpret_cast<const uint4*>(vg + (size_t)c*L_ + g*8);
    uint4 p1 = *reinterpret_cast<const uint4*>(vg + (size_t)(c+1)*L_ + g*8);
    const u16* e0 = reinterpret_cast<const u16*>(&p0);
    const u16* e1 = reinterpret_cast<const u16*>(&p1);
    #pragma unroll
    for (int j = 0; j < 8; ++j){
      int p = g*8 + j;
      u32 packed = ((u32)e0[j]) | (((u32)e1[j]) << 16);
      *reinterpret_cast<u32*>(vtb + vt_off(p, c)) = packed;
    }
  }
  __syncthreads();

  const int w = tid >> 6, lane = tid & 63;
  const int fr = lane & 15, kq = (lane >> 4) * 8;
  const int prow = w*16;
  f32x4 acc[24];
  #pragma unroll
  for (int j = 0; j < 24; ++j) acc[j] = (f32x4){0.f,0.f,0.f,0.f};

  const u16* ab = attn96 + ((size_t)bb*NH)*DH*96;
  #pragma unroll
  for (int n = 0; n < NH; ++n){
    bf16x8 af[3];
    #pragma unroll
    for (int s = 0; s < 3; ++s){
      int ep = s*32 + kq;                       // e' in [0,96)
      int ch = n*DH + (ep >= 48 ? ep - 48 : ep);
      af[s] = *reinterpret_cast<const bf16x8*>(vtb + vt_off(prow + fr, ch));
    }
    #pragma unroll
    for (int jj = 0; jj < 3; ++jj){
      const u16* arow = ab + ((size_t)n*DH + jj*16 + fr)*96;
      #pragma unroll
      for (int s = 0; s < 3; ++s){
        bf16x8 bf = *reinterpret_cast<const bf16x8*>(arow + s*32 + kq);
        acc[n*3+jj] = __builtin_amdgcn_mfma_f32_16x16x32_bf16(af[s], bf, acc[n*3+jj], 0, 0, 0);
      }
    }
  }

  // fused LN2: per-pixel stats (pixel = row), fully intra-wave
  f32x4 s = {0.f,0.f,0.f,0.f}, s2 = {0.f,0.f,0.f,0.f};
  #pragma unroll
  for (int j = 0; j < 24; ++j){ s += acc[j]; s2 += acc[j]*acc[j]; }
  #pragma unroll
  for (int m = 1; m < 16; m <<= 1){
    #pragma unroll
    for (int r = 0; r < 4; ++r){
      s[r]  += __shfl_xor(s[r],  m);
      s2[r] += __shfl_xor(s2[r], m);
    }
  }
  f32x4 mu, rstd;
  #pragma unroll
  for (int r = 0; r < 4; ++r){
    mu[r]   = s[r] * (1.f/C_);
    rstd[r] = rsqrtf(s2[r]*(1.f/C_) - mu[r]*mu[r] + 1e-5f);
  }
  const int pbase = l0 + prow + (lane>>4)*4;
  #pragma unroll
  for (int j = 0; j < 24; ++j){
    int c = j*16 + fr;
    float wc = w2[c], bc = b2[c];
    f32x4 o;
    #pragma unroll
    for (int r = 0; r < 4; ++r)
      o[r] = (acc[j][r] - mu[r]) * rstd[r] * wc + bc;
    *reinterpret_cast<f32x4*>(out + ((size_t)bb*C_ + c)*L_ + pbase) = o;
  }
}

extern "C" void kernel_launch(void* const* d_in, const int* in_sizes, int n_in,
                              void* d_out, int out_size, void* d_ws, size_t ws_size,
                              hipStream_t stream){
  const float* x     = (const float*)d_in[0];
  const float* wq    = (const float*)d_in[1];
  const float* wk    = (const float*)d_in[2];
  const float* wv    = (const float*)d_in[3];
  const float* dwq   = (const float*)d_in[4];
  const float* dwk   = (const float*)d_in[5];
  const float* dwv   = (const float*)d_in[6];
  const float* scale = (const float*)d_in[7];
  const float* ln1w  = (const float*)d_in[8];
  const float* ln1b  = (const float*)d_in[9];
  const float* ln2w  = (const float*)d_in[10];
  const float* ln2b  = (const float*)d_in[11];
  float* out = (float*)d_out;

  char* ws = (char*)d_ws;
  u16*   qkv    = (u16*)ws;                          // [3][B][C][L] bf16  = 150,994,944 B
  u16*   xt     = (u16*)(ws + 150994944);            // [B*L][C] bf16     =  50,331,648 B
  u16*   wc     = (u16*)(ws + 201326592);            // [1152][384] bf16  =     884,736 B
  float* sumsq  = (float*)(ws + 202211328);          // [2][B*C] f32      =      12,288 B
  float* Spart  = (float*)(ws + 202223616);          // [8][32][2304] f32 =   2,359,296 B
  u16*   attn96 = (u16*)(ws + 204582912);            // [32][48][96] u16  =     294,912 B

  k_cvt_w  <<<1728, 256, 0, stream>>>(wq, wk, wv, wc);
  k_ln1    <<<1024, 256, 0, stream>>>(x, ln1w, ln1b, xt);
  k_gemm   <<<9*512, 256, 0, stream>>>(wc, xt, qkv);
  k_dwconv <<<3*B_*C_, 256, 0, stream>>>(qkv, dwq, dwk, dwv, sumsq);
  k_qk     <<<SPLIT*B_*NH, 256, 0, stream>>>(qkv, Spart);
  k_softmax<<<B_*NH, 64, 0, stream>>>(Spart, sumsq, scale, attn96);
  k_av_ln2 <<<1024, 256, 0, stream>>>(qkv, attn96, ln2w, ln2b, out);
}

// Round 6
// 273.569 us; speedup vs baseline: 2.1585x; 1.0668x over previous
//
#include <hip/hip_runtime.h>
#include <hip/hip_bf16.h>
#include <stdint.h>

#define B_ 4
#define C_ 384
#define H_ 128
#define W_ 128
#define L_ (H_*W_)      // 16384
#define NH 8
#define DH 48           // C_/NH
#define SPLIT 8

typedef __attribute__((ext_vector_type(8))) short bf16x8;
typedef __attribute__((ext_vector_type(4))) float f32x4;
typedef unsigned short u16;
typedef unsigned int u32;

__device__ __forceinline__ float bf2f(u16 v){
  union { float f; u32 u; } x; x.u = ((u32)v) << 16; return x.f;
}
__device__ __forceinline__ u16 f2bf(float f){
  __hip_bfloat16 h = __float2bfloat16(f);
  return *reinterpret_cast<u16*>(&h);
}

#define GLOAD_LDS16(g, l) \
  __builtin_amdgcn_global_load_lds((const __attribute__((address_space(1))) u32*)(g), \
                                   (__attribute__((address_space(3))) u32*)(l), 16, 0, 0)

// ---------------- K0: convert 1x1 conv weights to bf16, concat [1152][384] ----------------
__global__ __launch_bounds__(256) void k_cvt_w(const float* __restrict__ wq,
                                               const float* __restrict__ wk,
                                               const float* __restrict__ wv,
                                               u16* __restrict__ wc){
  int i = blockIdx.x * 256 + threadIdx.x;
  if (i >= 3*C_*C_) return;
  int m = i / C_;
  int c = i - m*C_;
  const float* src = (m < C_) ? wq : (m < 2*C_) ? wk : wv;
  int mm = (m >= 2*C_) ? m - 2*C_ : (m >= C_) ? m - C_ : m;
  wc[i] = f2bf(src[mm*C_ + c]);
}

// ---------------- K1: LayerNorm over C, write transposed bf16 [B*L][C] ----------------
__global__ __launch_bounds__(256) void k_ln1(const float* __restrict__ x,
                                             const float* __restrict__ w,
                                             const float* __restrict__ b,
                                             u16* __restrict__ xt){
  const int tid = threadIdx.x;
  const int bb = blockIdx.x >> 8;          // 256 blocks per batch
  const int l0 = (blockIdx.x & 255) << 6;  // 64-pixel tile
  const int pg = tid >> 4;                 // 0..15, pixels pg*4..pg*4+3
  const int cg = tid & 15;                 // 0..15, channels cg*24..cg*24+23
  const int c0 = cg * 24;
  const float* xp = x + (size_t)bb*C_*L_ + (size_t)c0*L_ + l0 + pg*4;

  f32x4 vals[24];
  #pragma unroll
  for (int ci = 0; ci < 24; ++ci)
    vals[ci] = *reinterpret_cast<const f32x4*>(xp + (size_t)ci*L_);

  f32x4 s = {0.f,0.f,0.f,0.f}, s2 = {0.f,0.f,0.f,0.f};
  #pragma unroll
  for (int ci = 0; ci < 24; ++ci){ s += vals[ci]; s2 += vals[ci]*vals[ci]; }
  #pragma unroll
  for (int m = 1; m < 16; m <<= 1){
    #pragma unroll
    for (int r = 0; r < 4; ++r){
      s[r]  += __shfl_xor(s[r],  m);
      s2[r] += __shfl_xor(s2[r], m);
    }
  }
  f32x4 mu, rstd;
  #pragma unroll
  for (int r = 0; r < 4; ++r){
    mu[r]   = s[r] * (1.f/C_);
    rstd[r] = rsqrtf(s2[r]*(1.f/C_) - mu[r]*mu[r] + 1e-5f);
  }

  u16* dst = xt + ((size_t)bb*L_ + l0 + pg*4)*C_ + c0;
  #pragma unroll
  for (int j = 0; j < 3; ++j){
    f32x4 w0 = *reinterpret_cast<const f32x4*>(w + c0 + j*8);
    f32x4 w1 = *reinterpret_cast<const f32x4*>(w + c0 + j*8 + 4);
    f32x4 b0 = *reinterpret_cast<const f32x4*>(b + c0 + j*8);
    f32x4 b1 = *reinterpret_cast<const f32x4*>(b + c0 + j*8 + 4);
    #pragma unroll
    for (int pp = 0; pp < 4; ++pp){
      uint4 pk;
      u16* tp = reinterpret_cast<u16*>(&pk);
      #pragma unroll
      for (int e = 0; e < 4; ++e)
        tp[e]   = f2bf((vals[j*8+e][pp]   - mu[pp]) * rstd[pp] * w0[e] + b0[e]);
      #pragma unroll
      for (int e = 0; e < 4; ++e)
        tp[4+e] = f2bf((vals[j*8+4+e][pp] - mu[pp]) * rstd[pp] * w1[e] + b1[e]);
      *reinterpret_cast<uint4*>(dst + (size_t)pp*C_ + j*8) = pk;
    }
  }
}

// ---------------- K2: GEMM qkv = Wc[1152x384] * xt^T -> [3][B][C][L] bf16 ----------------
// XCD-aware block remap (bijective, 4608 = 8*576): each XCD owns 64 consecutive bn,
// so an Xt B-tile is fetched into one L2 and reused by its 9 m-blocks.
// LDS swizzle (both-sides, rule 21): 16B chunk q of row stored from global chunk
// q^((row>>1)&3) into LINEAR dest; fragment read at slot kqi^((row>>1)&3).
// -> b128 reads hit all 8 bank positions (2 lanes each) = conflict-free minimum.
__global__ __launch_bounds__(256) void k_gemm(const u16* __restrict__ Wc,
                                              const u16* __restrict__ Xt,
                                              u16* __restrict__ qkv){
  __shared__ u16 As[128*32];
  __shared__ u16 Bs[128*32];
  const int tid = threadIdx.x;
  const int wg = (int)blockIdx.x;
  const int lin = (wg & 7) * 576 + (wg >> 3);
  const int bm = lin % 9;
  const int bn = lin / 9;
  const int m0 = bm * 128;
  const int n0 = bn * 128;
  const int w = tid >> 6, lane = tid & 63;
  const int wm = (w >> 1) * 64, wn = (w & 1) * 64;
  const int fr = lane & 15, kqi = lane >> 4;
  const int sslot = kqi ^ ((fr >> 1) & 3);   // swizzled 16B slot (row&7 == fr&7)

  f32x4 acc[4][4] = {};

  for (int k0 = 0; k0 < 384; k0 += 32){
    #pragma unroll
    for (int i = 0; i < 2; ++i){
      int idx = i*256 + tid;          // 0..511, 16B each
      int row = idx >> 2, q = idx & 3;
      int qs = q ^ ((row >> 1) & 3);
      GLOAD_LDS16(Wc + (size_t)(m0+row)*384 + k0 + qs*8, As + idx*8);
      GLOAD_LDS16(Xt + (size_t)(n0+row)*384 + k0 + qs*8, Bs + idx*8);
    }
    __syncthreads();
    bf16x8 af[4], bfm[4];
    #pragma unroll
    for (int i = 0; i < 4; ++i)
      af[i] = *reinterpret_cast<const bf16x8*>(As + (wm + i*16 + fr)*32 + sslot*8);
    #pragma unroll
    for (int j = 0; j < 4; ++j)
      bfm[j] = *reinterpret_cast<const bf16x8*>(Bs + (wn + j*16 + fr)*32 + sslot*8);
    #pragma unroll
    for (int i = 0; i < 4; ++i)
      #pragma unroll
      for (int j = 0; j < 4; ++j)
        acc[i][j] = __builtin_amdgcn_mfma_f32_16x16x32_bf16(af[i], bfm[j], acc[i][j], 0, 0, 0);
    __syncthreads();
  }

  #pragma unroll
  for (int i = 0; i < 4; ++i){
    int mbase = m0 + wm + i*16 + (lane >> 4) * 4;
    #pragma unroll
    for (int j = 0; j < 4; ++j){
      int n = n0 + wn + j*16 + fr;
      int bb = n >> 14, l = n & (L_-1);
      #pragma unroll
      for (int r = 0; r < 4; ++r){
        int m = mbase + r;
        int proj = (m >= 2*C_) ? 2 : (m >= C_) ? 1 : 0;
        int c = m - proj*C_;
        qkv[(((size_t)proj*B_ + bb)*C_ + c)*L_ + l] = f2bf(acc[i][j][r]);
      }
    }
  }
}

// ---------------- K3: depthwise 3x3 in-place + per-channel sumsq for q,k ----------------
__global__ __launch_bounds__(256) void k_dwconv(u16* __restrict__ qkv,
                                                const float* __restrict__ dwq,
                                                const float* __restrict__ dwk,
                                                const float* __restrict__ dwv,
                                                float* __restrict__ sumsq){
  __shared__ u16 pl[128*128];
  int pid = blockIdx.x;                  // t*B*C + b*C + c
  int t = pid / (B_*C_);
  int bc = pid - t*(B_*C_);
  int c = bc % C_;
  const float* dw = ((t == 0) ? dwq : (t == 1) ? dwk : dwv) + c*9;
  u16* plane = qkv + ((size_t)t*B_*C_ + bc) * L_;
  int tid = threadIdx.x;
  #pragma unroll
  for (int i = 0; i < 8; ++i){
    int idx = i*256 + tid;
    *reinterpret_cast<uint4*>(pl + idx*8) = *reinterpret_cast<const uint4*>(plane + idx*8);
  }
  float wgt[9];
  #pragma unroll
  for (int i = 0; i < 9; ++i) wgt[i] = dw[i];
  __syncthreads();

  const int tx = tid & 15;           // tile col: pixels tx*8..tx*8+7
  const int ty = tid >> 4;           // tile row: rows ty*8..ty*8+7
  const int lane = tid & 63;
  const int y0 = ty*8;

  float rv[3][8], rl[3], rr_[3];
  float ss = 0.f;

  #pragma unroll
  for (int i = 0; i < 10; ++i){
    const int sl = i % 3;
    int r = y0 - 1 + i;
    int rc = (r < 0) ? 0 : (r > 127 ? 127 : r);
    uint4 pk = *reinterpret_cast<const uint4*>(pl + rc*128 + tx*8);
    const u16* e = reinterpret_cast<const u16*>(&pk);
    bool oob = (r < 0) || (r > 127);
    #pragma unroll
    for (int k = 0; k < 8; ++k)
      rv[sl][k] = oob ? 0.f : bf2f(e[k]);
    float lft = __shfl(rv[sl][7], lane - 1);
    float rgt = __shfl(rv[sl][0], lane + 1);
    rl[sl]  = (tx == 0)  ? 0.f : lft;
    rr_[sl] = (tx == 15) ? 0.f : rgt;

    if (i >= 2){
      const int sa = (i-2) % 3, sb = (i-1) % 3, sc = i % 3;
      const int y = i - 2;
      float o[8];
      #pragma unroll
      for (int xx = 0; xx < 8; ++xx){
        float am1 = (xx == 0) ? rl[sa]  : rv[sa][xx-1];
        float ap1 = (xx == 7) ? rr_[sa] : rv[sa][xx+1];
        float bm1 = (xx == 0) ? rl[sb]  : rv[sb][xx-1];
        float bp1 = (xx == 7) ? rr_[sb] : rv[sb][xx+1];
        float cm1 = (xx == 0) ? rl[sc]  : rv[sc][xx-1];
        float cp1 = (xx == 7) ? rr_[sc] : rv[sc][xx+1];
        float a = wgt[0]*am1 + wgt[1]*rv[sa][xx] + wgt[2]*ap1
                + wgt[3]*bm1 + wgt[4]*rv[sb][xx] + wgt[5]*bp1
                + wgt[6]*cm1 + wgt[7]*rv[sc][xx] + wgt[8]*cp1;
        o[xx] = a;
        ss += a * a;
      }
      uint4 st;
      u16* sp = reinterpret_cast<u16*>(&st);
      #pragma unroll
      for (int xx = 0; xx < 8; ++xx) sp[xx] = f2bf(o[xx]);
      *reinterpret_cast<uint4*>(plane + (y0 + y)*128 + tx*8) = st;
    }
  }

  if (t < 2){
    #pragma unroll
    for (int off = 32; off > 0; off >>= 1) ss += __shfl_down(ss, off);
    __shared__ float red[4];
    if ((tid & 63) == 0) red[tid >> 6] = ss;
    __syncthreads();
    if (tid == 0) sumsq[t*(B_*C_) + bc] = red[0] + red[1] + red[2] + red[3];
  }
}

// ---------------- K4: attention logits (split-K over L), S_part[s][b][n][48][48] ----------------
__global__ __launch_bounds__(256) void k_qk(const u16* __restrict__ qkv,
                                            float* __restrict__ Spart){
  int gid = blockIdx.x;                 // (s*B + b)*NH + n
  int s = gid / (B_*NH);
  int bn = gid - s*(B_*NH);
  int b = bn / NH, n = bn - b*NH;
  const u16* qb = qkv + ((size_t)b*C_ + n*DH) * L_;
  const u16* kb = qkv + ((size_t)B_*C_ + (size_t)b*C_ + n*DH) * L_;
  int tid = threadIdx.x, w = tid >> 6, lane = tid & 63;
  int fr = lane & 15, kq = (lane >> 4) * 8;
  int l0 = s * (L_/SPLIT) + w * (L_/SPLIT/4);     // 2048/block, 512/wave
  f32x4 acc[3][3] = {};
  for (int kk = 0; kk < 512; kk += 32){
    int koff = l0 + kk + kq;
    bf16x8 af[3], bfm[3];
    #pragma unroll
    for (int i = 0; i < 3; ++i) af[i]  = *reinterpret_cast<const bf16x8*>(qb + (size_t)(i*16+fr)*L_ + koff);
    #pragma unroll
    for (int j = 0; j < 3; ++j) bfm[j] = *reinterpret_cast<const bf16x8*>(kb + (size_t)(j*16+fr)*L_ + koff);
    #pragma unroll
    for (int i = 0; i < 3; ++i)
      #pragma unroll
      for (int j = 0; j < 3; ++j)
        acc[i][j] = __builtin_amdgcn_mfma_f32_16x16x32_bf16(af[i], bfm[j], acc[i][j], 0, 0, 0);
  }
  __shared__ float red[48*48];
  for (int ww = 0; ww < 4; ++ww){
    if (w == ww){
      #pragma unroll
      for (int i = 0; i < 3; ++i)
        #pragma unroll
        for (int j = 0; j < 3; ++j)
          #pragma unroll
          for (int r = 0; r < 4; ++r){
            int row = i*16 + (lane >> 4)*4 + r;
            int col = j*16 + fr;
            if (ww == 0) red[row*48 + col] = acc[i][j][r];
            else         red[row*48 + col] += acc[i][j][r];
          }
    }
    __syncthreads();
  }
  float* dst = Spart + ((size_t)gid) * 2304;
  for (int idx = tid; idx < 2304; idx += 256) dst[idx] = red[idx];
}

// ---------------- K5: reduce split-K, fold L2 norms + scale, softmax -> bf16 hi|lo [d][96] ----------------
__global__ void k_softmax(const float* __restrict__ Spart,
                          const float* __restrict__ sumsq,
                          const float* __restrict__ scale,
                          u16* __restrict__ attn96){
  int bn = blockIdx.x;                  // b*NH + n
  int b = bn / NH, n = bn - b*NH;
  int i = threadIdx.x;
  if (i >= DH) return;
  const float* sq = sumsq + (size_t)b*C_ + n*DH;
  const float* sk = sumsq + (size_t)B_*C_ + (size_t)b*C_ + n*DH;
  float nq = fmaxf(sqrtf(sq[i]), 1e-12f);
  float sc = scale[n];
  float row[48];
  #pragma unroll
  for (int j = 0; j < DH; ++j){
    float acc = 0.f;
    #pragma unroll
    for (int s = 0; s < SPLIT; ++s)
      acc += Spart[((size_t)(s*(B_*NH) + bn))*2304 + i*48 + j];
    float nk = fmaxf(sqrtf(sk[j]), 1e-12f);
    row[j] = acc / (nq * nk) * sc;
  }
  float m = row[0];
  #pragma unroll
  for (int j = 1; j < DH; ++j) m = fmaxf(m, row[j]);
  float sum = 0.f;
  #pragma unroll
  for (int j = 0; j < DH; ++j){ row[j] = __expf(row[j] - m); sum += row[j]; }
  float inv = 1.f / sum;
  u16* dst = attn96 + ((size_t)bn)*DH*96 + i*96;     // row d=i: hi[0..48) | lo[48..96)
  #pragma unroll
  for (int j = 0; j < DH; ++j){
    float a = row[j] * inv;
    u16 hi = f2bf(a);
    float lo = a - bf2f(hi);
    dst[j]      = hi;
    dst[48 + j] = f2bf(lo);
  }
}

// ---------------- K6: out = attn @ v via MFMA (hi+lo split-K=96), fused LayerNorm ----------------
#define VT_STRIDE 784
__device__ __forceinline__ int vt_off(int p, int ch){
  return p*VT_STRIDE + ((p>>3)<<4) + 2*ch;
}
__global__ __launch_bounds__(256) void k_av_ln2(const u16* __restrict__ qkv,
                                                const u16* __restrict__ attn96,
                                                const float* __restrict__ w2,
                                                const float* __restrict__ b2,
                                                float* __restrict__ out){
  __shared__ u16 vt[(64*VT_STRIDE + 8*16)/2];     // 50304 B
  char* vtb = reinterpret_cast<char*>(vt);
  const int tid = threadIdx.x;
  const int bb = blockIdx.x >> 8;        // 256 tiles per batch
  const int l0 = (blockIdx.x & 255) << 6;
  const u16* vg = qkv + ((size_t)2*B_*C_ + (size_t)bb*C_)*L_ + l0;

  // stage v[c][l0..l0+63] -> vt[p][c] (transposed): channel-pairs, u32 writes
  #pragma unroll
  for (int it = 0; it < 6; ++it){
    int idx = it*256 + tid;            // 0..1535
    int cp = idx >> 3, g = idx & 7;    // cp: channel pair 0..191, g: pixel group
    int c = cp*2;
    uint4 p0 = *reinterpret_cast<const uint4*>(vg + (size_t)c*L_ + g*8);
    uint4 p1 = *reinterpret_cast<const uint4*>(vg + (size_t)(c+1)*L_ + g*8);
    const u16* e0 = reinterpret_cast<const u16*>(&p0);
    const u16* e1 = reinterpret_cast<const u16*>(&p1);
    #pragma unroll
    for (int j = 0; j < 8; ++j){
      int p = g*8 + j;
      u32 packed = ((u32)e0[j]) | (((u32)e1[j]) << 16);
      *reinterpret_cast<u32*>(vtb + vt_off(p, c)) = packed;
    }
  }
  __syncthreads();

  const int w = tid >> 6, lane = tid & 63;
  const int fr = lane & 15, kq = (lane >> 4) * 8;
  const int prow = w*16;
  f32x4 acc[24];
  #pragma unroll
  for (int j = 0; j < 24; ++j) acc[j] = (f32x4){0.f,0.f,0.f,0.f};

  const u16* ab = attn96 + ((size_t)bb*NH)*DH*96;
  #pragma unroll
  for (int n = 0; n < NH; ++n){
    bf16x8 af[3];
    #pragma unroll
    for (int s = 0; s < 3; ++s){
      int ep = s*32 + kq;                       // e' in [0,96)
      int ch = n*DH + (ep >= 48 ? ep - 48 : ep);
      af[s] = *reinterpret_cast<const bf16x8*>(vtb + vt_off(prow + fr, ch));
    }
    #pragma unroll
    for (int jj = 0; jj < 3; ++jj){
      const u16* arow = ab + ((size_t)n*DH + jj*16 + fr)*96;
      #pragma unroll
      for (int s = 0; s < 3; ++s){
        bf16x8 bf = *reinterpret_cast<const bf16x8*>(arow + s*32 + kq);
        acc[n*3+jj] = __builtin_amdgcn_mfma_f32_16x16x32_bf16(af[s], bf, acc[n*3+jj], 0, 0, 0);
      }
    }
  }

  // fused LN2: per-pixel stats (pixel = row), fully intra-wave
  f32x4 s = {0.f,0.f,0.f,0.f}, s2 = {0.f,0.f,0.f,0.f};
  #pragma unroll
  for (int j = 0; j < 24; ++j){ s += acc[j]; s2 += acc[j]*acc[j]; }
  #pragma unroll
  for (int m = 1; m < 16; m <<= 1){
    #pragma unroll
    for (int r = 0; r < 4; ++r){
      s[r]  += __shfl_xor(s[r],  m);
      s2[r] += __shfl_xor(s2[r], m);
    }
  }
  f32x4 mu, rstd;
  #pragma unroll
  for (int r = 0; r < 4; ++r){
    mu[r]   = s[r] * (1.f/C_);
    rstd[r] = rsqrtf(s2[r]*(1.f/C_) - mu[r]*mu[r] + 1e-5f);
  }
  const int pbase = l0 + prow + (lane>>4)*4;
  #pragma unroll
  for (int j = 0; j < 24; ++j){
    int c = j*16 + fr;
    float wc = w2[c], bc = b2[c];
    f32x4 o;
    #pragma unroll
    for (int r = 0; r < 4; ++r)
      o[r] = (acc[j][r] - mu[r]) * rstd[r] * wc + bc;
    *reinterpret_cast<f32x4*>(out + ((size_t)bb*C_ + c)*L_ + pbase) = o;
  }
}

extern "C" void kernel_launch(void* const* d_in, const int* in_sizes, int n_in,
                              void* d_out, int out_size, void* d_ws, size_t ws_size,
                              hipStream_t stream){
  const float* x     = (const float*)d_in[0];
  const float* wq    = (const float*)d_in[1];
  const float* wk    = (const float*)d_in[2];
  const float* wv    = (const float*)d_in[3];
  const float* dwq   = (const float*)d_in[4];
  const float* dwk   = (const float*)d_in[5];
  const float* dwv   = (const float*)d_in[6];
  const float* scale = (const float*)d_in[7];
  const float* ln1w  = (const float*)d_in[8];
  const float* ln1b  = (const float*)d_in[9];
  const float* ln2w  = (const float*)d_in[10];
  const float* ln2b  = (const float*)d_in[11];
  float* out = (float*)d_out;

  char* ws = (char*)d_ws;
  u16*   qkv    = (u16*)ws;                          // [3][B][C][L] bf16  = 150,994,944 B
  u16*   xt     = (u16*)(ws + 150994944);            // [B*L][C] bf16     =  50,331,648 B
  u16*   wc     = (u16*)(ws + 201326592);            // [1152][384] bf16  =     884,736 B
  float* sumsq  = (float*)(ws + 202211328);          // [2][B*C] f32      =      12,288 B
  float* Spart  = (float*)(ws + 202223616);          // [8][32][2304] f32 =   2,359,296 B
  u16*   attn96 = (u16*)(ws + 204582912);            // [32][48][96] u16  =     294,912 B

  k_cvt_w  <<<1728, 256, 0, stream>>>(wq, wk, wv, wc);
  k_ln1    <<<1024, 256, 0, stream>>>(x, ln1w, ln1b, xt);
  k_gemm   <<<9*512, 256, 0, stream>>>(wc, xt, qkv);
  k_dwconv <<<3*B_*C_, 256, 0, stream>>>(qkv, dwq, dwk, dwv, sumsq);
  k_qk     <<<SPLIT*B_*NH, 256, 0, stream>>>(qkv, Spart);
  k_softmax<<<B_*NH, 64, 0, stream>>>(Spart, sumsq, scale, attn96);
  k_av_ln2 <<<1024, 256, 0, stream>>>(qkv, attn96, ln2w, ln2b, out);
}

// Round 7
// 273.322 us; speedup vs baseline: 2.1604x; 1.0009x over previous
//
#include <hip/hip_runtime.h>
#include <hip/hip_bf16.h>
#include <stdint.h>

#define B_ 4
#define C_ 384
#define H_ 128
#define W_ 128
#define L_ (H_*W_)      // 16384
#define NH 8
#define DH 48           // C_/NH
#define SPLIT 8

typedef __attribute__((ext_vector_type(8))) short bf16x8;
typedef __attribute__((ext_vector_type(4))) float f32x4;
typedef unsigned short u16;
typedef unsigned int u32;

__device__ __forceinline__ float bf2f(u16 v){
  union { float f; u32 u; } x; x.u = ((u32)v) << 16; return x.f;
}
__device__ __forceinline__ u16 f2bf(float f){
  __hip_bfloat16 h = __float2bfloat16(f);
  return *reinterpret_cast<u16*>(&h);
}

#define GLOAD_LDS16(g, l) \
  __builtin_amdgcn_global_load_lds((const __attribute__((address_space(1))) u32*)(g), \
                                   (__attribute__((address_space(3))) u32*)(l), 16, 0, 0)

// ---------------- K0: convert 1x1 conv weights to bf16, concat [1152][384] ----------------
__global__ __launch_bounds__(256) void k_cvt_w(const float* __restrict__ wq,
                                               const float* __restrict__ wk,
                                               const float* __restrict__ wv,
                                               u16* __restrict__ wc){
  int i = blockIdx.x * 256 + threadIdx.x;
  if (i >= 3*C_*C_) return;
  int m = i / C_;
  int c = i - m*C_;
  const float* src = (m < C_) ? wq : (m < 2*C_) ? wk : wv;
  int mm = (m >= 2*C_) ? m - 2*C_ : (m >= C_) ? m - C_ : m;
  wc[i] = f2bf(src[mm*C_ + c]);
}

// ---------------- K1: LayerNorm over C, write transposed bf16 [B*L][C] ----------------
__global__ __launch_bounds__(256) void k_ln1(const float* __restrict__ x,
                                             const float* __restrict__ w,
                                             const float* __restrict__ b,
                                             u16* __restrict__ xt){
  const int tid = threadIdx.x;
  const int bb = blockIdx.x >> 8;          // 256 blocks per batch
  const int l0 = (blockIdx.x & 255) << 6;  // 64-pixel tile
  const int pg = tid >> 4;                 // 0..15, pixels pg*4..pg*4+3
  const int cg = tid & 15;                 // 0..15, channels cg*24..cg*24+23
  const int c0 = cg * 24;
  const float* xp = x + (size_t)bb*C_*L_ + (size_t)c0*L_ + l0 + pg*4;

  f32x4 vals[24];
  #pragma unroll
  for (int ci = 0; ci < 24; ++ci)
    vals[ci] = *reinterpret_cast<const f32x4*>(xp + (size_t)ci*L_);

  f32x4 s = {0.f,0.f,0.f,0.f}, s2 = {0.f,0.f,0.f,0.f};
  #pragma unroll
  for (int ci = 0; ci < 24; ++ci){ s += vals[ci]; s2 += vals[ci]*vals[ci]; }
  #pragma unroll
  for (int m = 1; m < 16; m <<= 1){
    #pragma unroll
    for (int r = 0; r < 4; ++r){
      s[r]  += __shfl_xor(s[r],  m);
      s2[r] += __shfl_xor(s2[r], m);
    }
  }
  f32x4 mu, rstd;
  #pragma unroll
  for (int r = 0; r < 4; ++r){
    mu[r]   = s[r] * (1.f/C_);
    rstd[r] = rsqrtf(s2[r]*(1.f/C_) - mu[r]*mu[r] + 1e-5f);
  }

  u16* dst = xt + ((size_t)bb*L_ + l0 + pg*4)*C_ + c0;
  #pragma unroll
  for (int j = 0; j < 3; ++j){
    f32x4 w0 = *reinterpret_cast<const f32x4*>(w + c0 + j*8);
    f32x4 w1 = *reinterpret_cast<const f32x4*>(w + c0 + j*8 + 4);
    f32x4 b0 = *reinterpret_cast<const f32x4*>(b + c0 + j*8);
    f32x4 b1 = *reinterpret_cast<const f32x4*>(b + c0 + j*8 + 4);
    #pragma unroll
    for (int pp = 0; pp < 4; ++pp){
      uint4 pk;
      u16* tp = reinterpret_cast<u16*>(&pk);
      #pragma unroll
      for (int e = 0; e < 4; ++e)
        tp[e]   = f2bf((vals[j*8+e][pp]   - mu[pp]) * rstd[pp] * w0[e] + b0[e]);
      #pragma unroll
      for (int e = 0; e < 4; ++e)
        tp[4+e] = f2bf((vals[j*8+4+e][pp] - mu[pp]) * rstd[pp] * w1[e] + b1[e]);
      *reinterpret_cast<uint4*>(dst + (size_t)pp*C_ + j*8) = pk;
    }
  }
}

// ---------------- K2: GEMM qkv = Wc[1152x384] * xt^T -> [3][B][C][L] bf16 ----------------
// XCD-aware bijective block remap; both-sides LDS swizzle (R6, conflict-free).
// NEW: triple-buffered LDS, 2-deep prefetch, one raw s_barrier per K-step with
// counted s_waitcnt vmcnt(4) (T3/T4) -- never drain vmcnt to 0 mid-loop.
#define SLOTE (128*32)   // u16 elements per operand slot (8 KB)
__global__ __launch_bounds__(256) void k_gemm(const u16* __restrict__ Wc,
                                              const u16* __restrict__ Xt,
                                              u16* __restrict__ qkv){
  __shared__ u16 As[3*SLOTE];
  __shared__ u16 Bs[3*SLOTE];
  const int tid = threadIdx.x;
  const int wg = (int)blockIdx.x;
  const int lin = (wg & 7) * 576 + (wg >> 3);
  const int bm = lin % 9;
  const int bn = lin / 9;
  const int m0 = bm * 128;
  const int n0 = bn * 128;
  const int w = tid >> 6, lane = tid & 63;
  const int wm = (w >> 1) * 64, wn = (w & 1) * 64;
  const int fr = lane & 15, kqi = lane >> 4;
  const int sslot = kqi ^ ((fr >> 1) & 3);   // swizzled 16B slot (row&7 == fr&7)

  f32x4 acc[4][4] = {};

#define STAGE(slot, k0) do { \
    _Pragma("unroll") \
    for (int i_ = 0; i_ < 2; ++i_){ \
      int idx_ = i_*256 + tid; \
      int row_ = idx_ >> 2, q_ = idx_ & 3; \
      int qs_ = q_ ^ ((row_ >> 1) & 3); \
      GLOAD_LDS16(Wc + (size_t)(m0+row_)*384 + (k0) + qs_*8, As + (slot)*SLOTE + idx_*8); \
      GLOAD_LDS16(Xt + (size_t)(n0+row_)*384 + (k0) + qs_*8, Bs + (slot)*SLOTE + idx_*8); \
    } } while(0)

  STAGE(0, 0);
  STAGE(1, 32);

  #pragma unroll
  for (int it = 0; it < 12; ++it){
    const int cur = it % 3;
    __builtin_amdgcn_sched_barrier(0);
    if (it < 11) asm volatile("s_waitcnt vmcnt(4)" ::: "memory");
    else         asm volatile("s_waitcnt vmcnt(0)" ::: "memory");
    __builtin_amdgcn_sched_barrier(0);
    __builtin_amdgcn_s_barrier();
    __builtin_amdgcn_sched_barrier(0);
    if (it + 2 < 12) STAGE((it+2)%3, (it+2)*32);

    const u16* Ab = As + cur*SLOTE;
    const u16* Bb = Bs + cur*SLOTE;
    bf16x8 af[4], bfm[4];
    #pragma unroll
    for (int i = 0; i < 4; ++i)
      af[i] = *reinterpret_cast<const bf16x8*>(Ab + (wm + i*16 + fr)*32 + sslot*8);
    #pragma unroll
    for (int j = 0; j < 4; ++j)
      bfm[j] = *reinterpret_cast<const bf16x8*>(Bb + (wn + j*16 + fr)*32 + sslot*8);
    #pragma unroll
    for (int i = 0; i < 4; ++i)
      #pragma unroll
      for (int j = 0; j < 4; ++j)
        acc[i][j] = __builtin_amdgcn_mfma_f32_16x16x32_bf16(af[i], bfm[j], acc[i][j], 0, 0, 0);
  }
#undef STAGE

  #pragma unroll
  for (int i = 0; i < 4; ++i){
    int mbase = m0 + wm + i*16 + (lane >> 4) * 4;
    #pragma unroll
    for (int j = 0; j < 4; ++j){
      int n = n0 + wn + j*16 + fr;
      int bb = n >> 14, l = n & (L_-1);
      #pragma unroll
      for (int r = 0; r < 4; ++r){
        int m = mbase + r;
        int proj = (m >= 2*C_) ? 2 : (m >= C_) ? 1 : 0;
        int c = m - proj*C_;
        qkv[(((size_t)proj*B_ + bb)*C_ + c)*L_ + l] = f2bf(acc[i][j][r]);
      }
    }
  }
}

// ---------------- K3: depthwise 3x3 in-place + per-channel sumsq for q,k ----------------
__global__ __launch_bounds__(256) void k_dwconv(u16* __restrict__ qkv,
                                                const float* __restrict__ dwq,
                                                const float* __restrict__ dwk,
                                                const float* __restrict__ dwv,
                                                float* __restrict__ sumsq){
  __shared__ u16 pl[128*128];
  int pid = blockIdx.x;                  // t*B*C + b*C + c
  int t = pid / (B_*C_);
  int bc = pid - t*(B_*C_);
  int c = bc % C_;
  const float* dw = ((t == 0) ? dwq : (t == 1) ? dwk : dwv) + c*9;
  u16* plane = qkv + ((size_t)t*B_*C_ + bc) * L_;
  int tid = threadIdx.x;
  #pragma unroll
  for (int i = 0; i < 8; ++i){
    int idx = i*256 + tid;
    *reinterpret_cast<uint4*>(pl + idx*8) = *reinterpret_cast<const uint4*>(plane + idx*8);
  }
  float wgt[9];
  #pragma unroll
  for (int i = 0; i < 9; ++i) wgt[i] = dw[i];
  __syncthreads();

  const int tx = tid & 15;           // tile col: pixels tx*8..tx*8+7
  const int ty = tid >> 4;           // tile row: rows ty*8..ty*8+7
  const int lane = tid & 63;
  const int y0 = ty*8;

  float rv[3][8], rl[3], rr_[3];
  float ss = 0.f;

  #pragma unroll
  for (int i = 0; i < 10; ++i){
    const int sl = i % 3;
    int r = y0 - 1 + i;
    int rc = (r < 0) ? 0 : (r > 127 ? 127 : r);
    uint4 pk = *reinterpret_cast<const uint4*>(pl + rc*128 + tx*8);
    const u16* e = reinterpret_cast<const u16*>(&pk);
    bool oob = (r < 0) || (r > 127);
    #pragma unroll
    for (int k = 0; k < 8; ++k)
      rv[sl][k] = oob ? 0.f : bf2f(e[k]);
    float lft = __shfl(rv[sl][7], lane - 1);
    float rgt = __shfl(rv[sl][0], lane + 1);
    rl[sl]  = (tx == 0)  ? 0.f : lft;
    rr_[sl] = (tx == 15) ? 0.f : rgt;

    if (i >= 2){
      const int sa = (i-2) % 3, sb = (i-1) % 3, sc = i % 3;
      const int y = i - 2;
      float o[8];
      #pragma unroll
      for (int xx = 0; xx < 8; ++xx){
        float am1 = (xx == 0) ? rl[sa]  : rv[sa][xx-1];
        float ap1 = (xx == 7) ? rr_[sa] : rv[sa][xx+1];
        float bm1 = (xx == 0) ? rl[sb]  : rv[sb][xx-1];
        float bp1 = (xx == 7) ? rr_[sb] : rv[sb][xx+1];
        float cm1 = (xx == 0) ? rl[sc]  : rv[sc][xx-1];
        float cp1 = (xx == 7) ? rr_[sc] : rv[sc][xx+1];
        float a = wgt[0]*am1 + wgt[1]*rv[sa][xx] + wgt[2]*ap1
                + wgt[3]*bm1 + wgt[4]*rv[sb][xx] + wgt[5]*bp1
                + wgt[6]*cm1 + wgt[7]*rv[sc][xx] + wgt[8]*cp1;
        o[xx] = a;
        ss += a * a;
      }
      uint4 st;
      u16* sp = reinterpret_cast<u16*>(&st);
      #pragma unroll
      for (int xx = 0; xx < 8; ++xx) sp[xx] = f2bf(o[xx]);
      *reinterpret_cast<uint4*>(plane + (y0 + y)*128 + tx*8) = st;
    }
  }

  if (t < 2){
    #pragma unroll
    for (int off = 32; off > 0; off >>= 1) ss += __shfl_down(ss, off);
    __shared__ float red[4];
    if ((tid & 63) == 0) red[tid >> 6] = ss;
    __syncthreads();
    if (tid == 0) sumsq[t*(B_*C_) + bc] = red[0] + red[1] + red[2] + red[3];
  }
}

// ---------------- K4: attention logits (split-K over L), S_part[s][b][n][48][48] ----------------
__global__ __launch_bounds__(256) void k_qk(const u16* __restrict__ qkv,
                                            float* __restrict__ Spart){
  int gid = blockIdx.x;                 // (s*B + b)*NH + n
  int s = gid / (B_*NH);
  int bn = gid - s*(B_*NH);
  int b = bn / NH, n = bn - b*NH;
  const u16* qb = qkv + ((size_t)b*C_ + n*DH) * L_;
  const u16* kb = qkv + ((size_t)B_*C_ + (size_t)b*C_ + n*DH) * L_;
  int tid = threadIdx.x, w = tid >> 6, lane = tid & 63;
  int fr = lane & 15, kq = (lane >> 4) * 8;
  int l0 = s * (L_/SPLIT) + w * (L_/SPLIT/4);     // 2048/block, 512/wave
  f32x4 acc[3][3] = {};
  for (int kk = 0; kk < 512; kk += 32){
    int koff = l0 + kk + kq;
    bf16x8 af[3], bfm[3];
    #pragma unroll
    for (int i = 0; i < 3; ++i) af[i]  = *reinterpret_cast<const bf16x8*>(qb + (size_t)(i*16+fr)*L_ + koff);
    #pragma unroll
    for (int j = 0; j < 3; ++j) bfm[j] = *reinterpret_cast<const bf16x8*>(kb + (size_t)(j*16+fr)*L_ + koff);
    #pragma unroll
    for (int i = 0; i < 3; ++i)
      #pragma unroll
      for (int j = 0; j < 3; ++j)
        acc[i][j] = __builtin_amdgcn_mfma_f32_16x16x32_bf16(af[i], bfm[j], acc[i][j], 0, 0, 0);
  }
  __shared__ float red[48*48];
  for (int ww = 0; ww < 4; ++ww){
    if (w == ww){
      #pragma unroll
      for (int i = 0; i < 3; ++i)
        #pragma unroll
        for (int j = 0; j < 3; ++j)
          #pragma unroll
          for (int r = 0; r < 4; ++r){
            int row = i*16 + (lane >> 4)*4 + r;
            int col = j*16 + fr;
            if (ww == 0) red[row*48 + col] = acc[i][j][r];
            else         red[row*48 + col] += acc[i][j][r];
          }
    }
    __syncthreads();
  }
  float* dst = Spart + ((size_t)gid) * 2304;
  for (int idx = tid; idx < 2304; idx += 256) dst[idx] = red[idx];
}

// ---------------- K5: reduce split-K, fold L2 norms + scale, softmax -> bf16 hi|lo [d][96] ----------------
__global__ void k_softmax(const float* __restrict__ Spart,
                          const float* __restrict__ sumsq,
                          const float* __restrict__ scale,
                          u16* __restrict__ attn96){
  int bn = blockIdx.x;                  // b*NH + n
  int b = bn / NH, n = bn - b*NH;
  int i = threadIdx.x;
  if (i >= DH) return;
  const float* sq = sumsq + (size_t)b*C_ + n*DH;
  const float* sk = sumsq + (size_t)B_*C_ + (size_t)b*C_ + n*DH;
  float nq = fmaxf(sqrtf(sq[i]), 1e-12f);
  float sc = scale[n];
  float row[48];
  #pragma unroll
  for (int j = 0; j < DH; ++j){
    float acc = 0.f;
    #pragma unroll
    for (int s = 0; s < SPLIT; ++s)
      acc += Spart[((size_t)(s*(B_*NH) + bn))*2304 + i*48 + j];
    float nk = fmaxf(sqrtf(sk[j]), 1e-12f);
    row[j] = acc / (nq * nk) * sc;
  }
  float m = row[0];
  #pragma unroll
  for (int j = 1; j < DH; ++j) m = fmaxf(m, row[j]);
  float sum = 0.f;
  #pragma unroll
  for (int j = 0; j < DH; ++j){ row[j] = __expf(row[j] - m); sum += row[j]; }
  float inv = 1.f / sum;
  u16* dst = attn96 + ((size_t)bn)*DH*96 + i*96;     // row d=i: hi[0..48) | lo[48..96)
  #pragma unroll
  for (int j = 0; j < DH; ++j){
    float a = row[j] * inv;
    u16 hi = f2bf(a);
    float lo = a - bf2f(hi);
    dst[j]      = hi;
    dst[48 + j] = f2bf(lo);
  }
}

// ---------------- K6: out = attn @ v via MFMA (hi+lo split-K=96), fused LayerNorm ----------------
#define VT_STRIDE 784
__device__ __forceinline__ int vt_off(int p, int ch){
  return p*VT_STRIDE + ((p>>3)<<4) + 2*ch;
}
__global__ __launch_bounds__(256) void k_av_ln2(const u16* __restrict__ qkv,
                                                const u16* __restrict__ attn96,
                                                const float* __restrict__ w2,
                                                const float* __restrict__ b2,
                                                float* __restrict__ out){
  __shared__ u16 vt[(64*VT_STRIDE + 8*16)/2];     // 50304 B
  char* vtb = reinterpret_cast<char*>(vt);
  const int tid = threadIdx.x;
  const int bb = blockIdx.x >> 8;        // 256 tiles per batch
  const int l0 = (blockIdx.x & 255) << 6;
  const u16* vg = qkv + ((size_t)2*B_*C_ + (size_t)bb*C_)*L_ + l0;

  // stage v[c][l0..l0+63] -> vt[p][c] (transposed): channel-pairs, u32 writes
  #pragma unroll
  for (int it = 0; it < 6; ++it){
    int idx = it*256 + tid;            // 0..1535
    int cp = idx >> 3, g = idx & 7;    // cp: channel pair 0..191, g: pixel group
    int c = cp*2;
    uint4 p0 = *reinterpret_cast<const uint4*>(vg + (size_t)c*L_ + g*8);
    uint4 p1 = *reinterpret_cast<const uint4*>(vg + (size_t)(c+1)*L_ + g*8);
    const u16* e0 = reinterpret_cast<const u16*>(&p0);
    const u16* e1 = reinterpret_cast<const u16*>(&p1);
    #pragma unroll
    for (int j = 0; j < 8; ++j){
      int p = g*8 + j;
      u32 packed = ((u32)e0[j]) | (((u32)e1[j]) << 16);
      *reinterpret_cast<u32*>(vtb + vt_off(p, c)) = packed;
    }
  }
  __syncthreads();

  const int w = tid >> 6, lane = tid & 63;
  const int fr = lane & 15, kq = (lane >> 4) * 8;
  const int prow = w*16;
  f32x4 acc[24];
  #pragma unroll
  for (int j = 0; j < 24; ++j) acc[j] = (f32x4){0.f,0.f,0.f,0.f};

  const u16* ab = attn96 + ((size_t)bb*NH)*DH*96;
  #pragma unroll
  for (int n = 0; n < NH; ++n){
    bf16x8 af[3];
    #pragma unroll
    for (int s = 0; s < 3; ++s){
      int ep = s*32 + kq;                       // e' in [0,96)
      int ch = n*DH + (ep >= 48 ? ep - 48 : ep);
      af[s] = *reinterpret_cast<const bf16x8*>(vtb + vt_off(prow + fr, ch));
    }
    #pragma unroll
    for (int jj = 0; jj < 3; ++jj){
      const u16* arow = ab + ((size_t)n*DH + jj*16 + fr)*96;
      #pragma unroll
      for (int s = 0; s < 3; ++s){
        bf16x8 bf = *reinterpret_cast<const bf16x8*>(arow + s*32 + kq);
        acc[n*3+jj] = __builtin_amdgcn_mfma_f32_16x16x32_bf16(af[s], bf, acc[n*3+jj], 0, 0, 0);
      }
    }
  }

  // fused LN2: per-pixel stats (pixel = row), fully intra-wave
  f32x4 s = {0.f,0.f,0.f,0.f}, s2 = {0.f,0.f,0.f,0.f};
  #pragma unroll
  for (int j = 0; j < 24; ++j){ s += acc[j]; s2 += acc[j]*acc[j]; }
  #pragma unroll
  for (int m = 1; m < 16; m <<= 1){
    #pragma unroll
    for (int r = 0; r < 4; ++r){
      s[r]  += __shfl_xor(s[r],  m);
      s2[r] += __shfl_xor(s2[r], m);
    }
  }
  f32x4 mu, rstd;
  #pragma unroll
  for (int r = 0; r < 4; ++r){
    mu[r]   = s[r] * (1.f/C_);
    rstd[r] = rsqrtf(s2[r]*(1.f/C_) - mu[r]*mu[r] + 1e-5f);
  }
  const int pbase = l0 + prow + (lane>>4)*4;
  #pragma unroll
  for (int j = 0; j < 24; ++j){
    int c = j*16 + fr;
    float wc = w2[c], bc = b2[c];
    f32x4 o;
    #pragma unroll
    for (int r = 0; r < 4; ++r)
      o[r] = (acc[j][r] - mu[r]) * rstd[r] * wc + bc;
    *reinterpret_cast<f32x4*>(out + ((size_t)bb*C_ + c)*L_ + pbase) = o;
  }
}

extern "C" void kernel_launch(void* const* d_in, const int* in_sizes, int n_in,
                              void* d_out, int out_size, void* d_ws, size_t ws_size,
                              hipStream_t stream){
  const float* x     = (const float*)d_in[0];
  const float* wq    = (const float*)d_in[1];
  const float* wk    = (const float*)d_in[2];
  const float* wv    = (const float*)d_in[3];
  const float* dwq   = (const float*)d_in[4];
  const float* dwk   = (const float*)d_in[5];
  const float* dwv   = (const float*)d_in[6];
  const float* scale = (const float*)d_in[7];
  const float* ln1w  = (const float*)d_in[8];
  const float* ln1b  = (const float*)d_in[9];
  const float* ln2w  = (const float*)d_in[10];
  const float* ln2b  = (const float*)d_in[11];
  float* out = (float*)d_out;

  char* ws = (char*)d_ws;
  u16*   qkv    = (u16*)ws;                          // [3][B][C][L] bf16  = 150,994,944 B
  u16*   xt     = (u16*)(ws + 150994944);            // [B*L][C] bf16     =  50,331,648 B
  u16*   wc     = (u16*)(ws + 201326592);            // [1152][384] bf16  =     884,736 B
  float* sumsq  = (float*)(ws + 202211328);          // [2][B*C] f32      =      12,288 B
  float* Spart  = (float*)(ws + 202223616);          // [8][32][2304] f32 =   2,359,296 B
  u16*   attn96 = (u16*)(ws + 204582912);            // [32][48][96] u16  =     294,912 B

  k_cvt_w  <<<1728, 256, 0, stream>>>(wq, wk, wv, wc);
  k_ln1    <<<1024, 256, 0, stream>>>(x, ln1w, ln1b, xt);
  k_gemm   <<<9*512, 256, 0, stream>>>(wc, xt, qkv);
  k_dwconv <<<3*B_*C_, 256, 0, stream>>>(qkv, dwq, dwk, dwv, sumsq);
  k_qk     <<<SPLIT*B_*NH, 256, 0, stream>>>(qkv, Spart);
  k_softmax<<<B_*NH, 64, 0, stream>>>(Spart, sumsq, scale, attn96);
  k_av_ln2 <<<1024, 256, 0, stream>>>(qkv, attn96, ln2w, ln2b, out);
}

// Round 8
// 261.780 us; speedup vs baseline: 2.2557x; 1.0441x over previous
//
#include <hip/hip_runtime.h>
#include <hip/hip_bf16.h>
#include <stdint.h>

#define B_ 4
#define C_ 384
#define H_ 128
#define W_ 128
#define L_ (H_*W_)      // 16384
#define NH 8
#define DH 48           // C_/NH
#define SPLIT 8

typedef __attribute__((ext_vector_type(8))) short bf16x8;
typedef __attribute__((ext_vector_type(4))) float f32x4;
typedef unsigned short u16;
typedef unsigned int u32;

__device__ __forceinline__ float bf2f(u16 v){
  union { float f; u32 u; } x; x.u = ((u32)v) << 16; return x.f;
}
__device__ __forceinline__ u16 f2bf(float f){
  __hip_bfloat16 h = __float2bfloat16(f);
  return *reinterpret_cast<u16*>(&h);
}

#define GLOAD_LDS16(g, l) \
  __builtin_amdgcn_global_load_lds((const __attribute__((address_space(1))) u32*)(g), \
                                   (__attribute__((address_space(3))) u32*)(l), 16, 0, 0)

// ---------------- K0: convert 1x1 conv weights to bf16, concat [1152][384] ----------------
__global__ __launch_bounds__(256) void k_cvt_w(const float* __restrict__ wq,
                                               const float* __restrict__ wk,
                                               const float* __restrict__ wv,
                                               u16* __restrict__ wc){
  int i = blockIdx.x * 256 + threadIdx.x;
  if (i >= 3*C_*C_) return;
  int m = i / C_;
  int c = i - m*C_;
  const float* src = (m < C_) ? wq : (m < 2*C_) ? wk : wv;
  int mm = (m >= 2*C_) ? m - 2*C_ : (m >= C_) ? m - C_ : m;
  wc[i] = f2bf(src[mm*C_ + c]);
}

// ---------------- K1: LayerNorm over C, write transposed bf16 [B*L][C] ----------------
__global__ __launch_bounds__(256) void k_ln1(const float* __restrict__ x,
                                             const float* __restrict__ w,
                                             const float* __restrict__ b,
                                             u16* __restrict__ xt){
  const int tid = threadIdx.x;
  const int bb = blockIdx.x >> 8;          // 256 blocks per batch
  const int l0 = (blockIdx.x & 255) << 6;  // 64-pixel tile
  const int pg = tid >> 4;                 // 0..15, pixels pg*4..pg*4+3
  const int cg = tid & 15;                 // 0..15, channels cg*24..cg*24+23
  const int c0 = cg * 24;
  const float* xp = x + (size_t)bb*C_*L_ + (size_t)c0*L_ + l0 + pg*4;

  f32x4 vals[24];
  #pragma unroll
  for (int ci = 0; ci < 24; ++ci)
    vals[ci] = *reinterpret_cast<const f32x4*>(xp + (size_t)ci*L_);

  f32x4 s = {0.f,0.f,0.f,0.f}, s2 = {0.f,0.f,0.f,0.f};
  #pragma unroll
  for (int ci = 0; ci < 24; ++ci){ s += vals[ci]; s2 += vals[ci]*vals[ci]; }
  #pragma unroll
  for (int m = 1; m < 16; m <<= 1){
    #pragma unroll
    for (int r = 0; r < 4; ++r){
      s[r]  += __shfl_xor(s[r],  m);
      s2[r] += __shfl_xor(s2[r], m);
    }
  }
  f32x4 mu, rstd;
  #pragma unroll
  for (int r = 0; r < 4; ++r){
    mu[r]   = s[r] * (1.f/C_);
    rstd[r] = rsqrtf(s2[r]*(1.f/C_) - mu[r]*mu[r] + 1e-5f);
  }

  u16* dst = xt + ((size_t)bb*L_ + l0 + pg*4)*C_ + c0;
  #pragma unroll
  for (int j = 0; j < 3; ++j){
    f32x4 w0 = *reinterpret_cast<const f32x4*>(w + c0 + j*8);
    f32x4 w1 = *reinterpret_cast<const f32x4*>(w + c0 + j*8 + 4);
    f32x4 b0 = *reinterpret_cast<const f32x4*>(b + c0 + j*8);
    f32x4 b1 = *reinterpret_cast<const f32x4*>(b + c0 + j*8 + 4);
    #pragma unroll
    for (int pp = 0; pp < 4; ++pp){
      uint4 pk;
      u16* tp = reinterpret_cast<u16*>(&pk);
      #pragma unroll
      for (int e = 0; e < 4; ++e)
        tp[e]   = f2bf((vals[j*8+e][pp]   - mu[pp]) * rstd[pp] * w0[e] + b0[e]);
      #pragma unroll
      for (int e = 0; e < 4; ++e)
        tp[4+e] = f2bf((vals[j*8+4+e][pp] - mu[pp]) * rstd[pp] * w1[e] + b1[e]);
      *reinterpret_cast<uint4*>(dst + (size_t)pp*C_ + j*8) = pk;
    }
  }
}

// ---------------- K2: GEMM qkv = Wc[1152x384] * xt^T -> [3][B][C][L] bf16 ----------------
// 128x256 tile, 512 threads / 8 waves (2M x 4N); triple-buffered LDS with counted
// s_waitcnt vmcnt(3) (1 A + 2 B chunks/thread/stage); both-sides LDS swizzle;
// XCD-aware bijective remap (2304 = 8*288, 32 consecutive bn per XCD).
#define SLOTA (128*32)   // u16 elements per A slot (8 KB)
#define SLOTB (256*32)   // u16 elements per B slot (16 KB)
__global__ __launch_bounds__(512) void k_gemm(const u16* __restrict__ Wc,
                                              const u16* __restrict__ Xt,
                                              u16* __restrict__ qkv){
  __shared__ u16 As[3*SLOTA];   // 24 KB
  __shared__ u16 Bs[3*SLOTB];   // 48 KB
  const int tid = threadIdx.x;
  const int wg = (int)blockIdx.x;
  const int lin = (wg & 7) * 288 + (wg >> 3);
  const int bm = lin % 9;
  const int bn = lin / 9;
  const int m0 = bm * 128;
  const int n0 = bn * 256;
  const int w = tid >> 6, lane = tid & 63;
  const int wm = (w >> 2) * 64, wn = (w & 3) * 64;
  const int fr = lane & 15, kqi = lane >> 4;
  const int sslot = kqi ^ ((fr >> 1) & 3);   // swizzled 16B slot (row&7 == fr&7)

  f32x4 acc[4][4] = {};

#define STAGE(slot, k0) do { \
    { int rowA_ = tid >> 2, qA_ = tid & 3; \
      int qsA_ = qA_ ^ ((rowA_ >> 1) & 3); \
      GLOAD_LDS16(Wc + (size_t)(m0+rowA_)*384 + (k0) + qsA_*8, As + (slot)*SLOTA + tid*8); } \
    _Pragma("unroll") \
    for (int i_ = 0; i_ < 2; ++i_){ \
      int idx_ = i_*512 + tid; \
      int row_ = idx_ >> 2, q_ = idx_ & 3; \
      int qs_ = q_ ^ ((row_ >> 1) & 3); \
      GLOAD_LDS16(Xt + (size_t)(n0+row_)*384 + (k0) + qs_*8, Bs + (slot)*SLOTB + idx_*8); \
    } } while(0)

  STAGE(0, 0);
  STAGE(1, 32);

  #pragma unroll
  for (int it = 0; it < 12; ++it){
    const int cur = it % 3;
    __builtin_amdgcn_sched_barrier(0);
    if (it < 11) asm volatile("s_waitcnt vmcnt(3)" ::: "memory");
    else         asm volatile("s_waitcnt vmcnt(0)" ::: "memory");
    __builtin_amdgcn_sched_barrier(0);
    __builtin_amdgcn_s_barrier();
    __builtin_amdgcn_sched_barrier(0);
    if (it + 2 < 12) STAGE((it+2)%3, (it+2)*32);

    const u16* Ab = As + cur*SLOTA;
    const u16* Bb = Bs + cur*SLOTB;
    bf16x8 af[4], bfm[4];
    #pragma unroll
    for (int i = 0; i < 4; ++i)
      af[i] = *reinterpret_cast<const bf16x8*>(Ab + (wm + i*16 + fr)*32 + sslot*8);
    #pragma unroll
    for (int j = 0; j < 4; ++j)
      bfm[j] = *reinterpret_cast<const bf16x8*>(Bb + (wn + j*16 + fr)*32 + sslot*8);
    #pragma unroll
    for (int i = 0; i < 4; ++i)
      #pragma unroll
      for (int j = 0; j < 4; ++j)
        acc[i][j] = __builtin_amdgcn_mfma_f32_16x16x32_bf16(af[i], bfm[j], acc[i][j], 0, 0, 0);
  }
#undef STAGE

  #pragma unroll
  for (int i = 0; i < 4; ++i){
    int mbase = m0 + wm + i*16 + (lane >> 4) * 4;
    #pragma unroll
    for (int j = 0; j < 4; ++j){
      int n = n0 + wn + j*16 + fr;
      int bb = n >> 14, l = n & (L_-1);
      #pragma unroll
      for (int r = 0; r < 4; ++r){
        int m = mbase + r;
        int proj = (m >= 2*C_) ? 2 : (m >= C_) ? 1 : 0;
        int c = m - proj*C_;
        qkv[(((size_t)proj*B_ + bb)*C_ + c)*L_ + l] = f2bf(acc[i][j][r]);
      }
    }
  }
}

// ---------------- K3: depthwise 3x3 in-place + per-channel sumsq for q,k ----------------
__global__ __launch_bounds__(256) void k_dwconv(u16* __restrict__ qkv,
                                                const float* __restrict__ dwq,
                                                const float* __restrict__ dwk,
                                                const float* __restrict__ dwv,
                                                float* __restrict__ sumsq){
  __shared__ u16 pl[128*128];
  int pid = blockIdx.x;                  // t*B*C + b*C + c
  int t = pid / (B_*C_);
  int bc = pid - t*(B_*C_);
  int c = bc % C_;
  const float* dw = ((t == 0) ? dwq : (t == 1) ? dwk : dwv) + c*9;
  u16* plane = qkv + ((size_t)t*B_*C_ + bc) * L_;
  int tid = threadIdx.x;
  #pragma unroll
  for (int i = 0; i < 8; ++i){
    int idx = i*256 + tid;
    *reinterpret_cast<uint4*>(pl + idx*8) = *reinterpret_cast<const uint4*>(plane + idx*8);
  }
  float wgt[9];
  #pragma unroll
  for (int i = 0; i < 9; ++i) wgt[i] = dw[i];
  __syncthreads();

  const int tx = tid & 15;           // tile col: pixels tx*8..tx*8+7
  const int ty = tid >> 4;           // tile row: rows ty*8..ty*8+7
  const int lane = tid & 63;
  const int y0 = ty*8;

  float rv[3][8], rl[3], rr_[3];
  float ss = 0.f;

  #pragma unroll
  for (int i = 0; i < 10; ++i){
    const int sl = i % 3;
    int r = y0 - 1 + i;
    int rc = (r < 0) ? 0 : (r > 127 ? 127 : r);
    uint4 pk = *reinterpret_cast<const uint4*>(pl + rc*128 + tx*8);
    const u16* e = reinterpret_cast<const u16*>(&pk);
    bool oob = (r < 0) || (r > 127);
    #pragma unroll
    for (int k = 0; k < 8; ++k)
      rv[sl][k] = oob ? 0.f : bf2f(e[k]);
    float lft = __shfl(rv[sl][7], lane - 1);
    float rgt = __shfl(rv[sl][0], lane + 1);
    rl[sl]  = (tx == 0)  ? 0.f : lft;
    rr_[sl] = (tx == 15) ? 0.f : rgt;

    if (i >= 2){
      const int sa = (i-2) % 3, sb = (i-1) % 3, sc = i % 3;
      const int y = i - 2;
      float o[8];
      #pragma unroll
      for (int xx = 0; xx < 8; ++xx){
        float am1 = (xx == 0) ? rl[sa]  : rv[sa][xx-1];
        float ap1 = (xx == 7) ? rr_[sa] : rv[sa][xx+1];
        float bm1 = (xx == 0) ? rl[sb]  : rv[sb][xx-1];
        float bp1 = (xx == 7) ? rr_[sb] : rv[sb][xx+1];
        float cm1 = (xx == 0) ? rl[sc]  : rv[sc][xx-1];
        float cp1 = (xx == 7) ? rr_[sc] : rv[sc][xx+1];
        float a = wgt[0]*am1 + wgt[1]*rv[sa][xx] + wgt[2]*ap1
                + wgt[3]*bm1 + wgt[4]*rv[sb][xx] + wgt[5]*bp1
                + wgt[6]*cm1 + wgt[7]*rv[sc][xx] + wgt[8]*cp1;
        o[xx] = a;
        ss += a * a;
      }
      uint4 st;
      u16* sp = reinterpret_cast<u16*>(&st);
      #pragma unroll
      for (int xx = 0; xx < 8; ++xx) sp[xx] = f2bf(o[xx]);
      *reinterpret_cast<uint4*>(plane + (y0 + y)*128 + tx*8) = st;
    }
  }

  if (t < 2){
    #pragma unroll
    for (int off = 32; off > 0; off >>= 1) ss += __shfl_down(ss, off);
    __shared__ float red[4];
    if ((tid & 63) == 0) red[tid >> 6] = ss;
    __syncthreads();
    if (tid == 0) sumsq[t*(B_*C_) + bc] = red[0] + red[1] + red[2] + red[3];
  }
}

// ---------------- K4: attention logits (split-K over L), S_part[s][b][n][48][48] ----------------
__global__ __launch_bounds__(256) void k_qk(const u16* __restrict__ qkv,
                                            float* __restrict__ Spart){
  int gid = blockIdx.x;                 // (s*B + b)*NH + n
  int s = gid / (B_*NH);
  int bn = gid - s*(B_*NH);
  int b = bn / NH, n = bn - b*NH;
  const u16* qb = qkv + ((size_t)b*C_ + n*DH) * L_;
  const u16* kb = qkv + ((size_t)B_*C_ + (size_t)b*C_ + n*DH) * L_;
  int tid = threadIdx.x, w = tid >> 6, lane = tid & 63;
  int fr = lane & 15, kq = (lane >> 4) * 8;
  int l0 = s * (L_/SPLIT) + w * (L_/SPLIT/4);     // 2048/block, 512/wave
  f32x4 acc[3][3] = {};
  for (int kk = 0; kk < 512; kk += 32){
    int koff = l0 + kk + kq;
    bf16x8 af[3], bfm[3];
    #pragma unroll
    for (int i = 0; i < 3; ++i) af[i]  = *reinterpret_cast<const bf16x8*>(qb + (size_t)(i*16+fr)*L_ + koff);
    #pragma unroll
    for (int j = 0; j < 3; ++j) bfm[j] = *reinterpret_cast<const bf16x8*>(kb + (size_t)(j*16+fr)*L_ + koff);
    #pragma unroll
    for (int i = 0; i < 3; ++i)
      #pragma unroll
      for (int j = 0; j < 3; ++j)
        acc[i][j] = __builtin_amdgcn_mfma_f32_16x16x32_bf16(af[i], bfm[j], acc[i][j], 0, 0, 0);
  }
  __shared__ float red[48*48];
  for (int ww = 0; ww < 4; ++ww){
    if (w == ww){
      #pragma unroll
      for (int i = 0; i < 3; ++i)
        #pragma unroll
        for (int j = 0; j < 3; ++j)
          #pragma unroll
          for (int r = 0; r < 4; ++r){
            int row = i*16 + (lane >> 4)*4 + r;
            int col = j*16 + fr;
            if (ww == 0) red[row*48 + col] = acc[i][j][r];
            else         red[row*48 + col] += acc[i][j][r];
          }
    }
    __syncthreads();
  }
  float* dst = Spart + ((size_t)gid) * 2304;
  for (int idx = tid; idx < 2304; idx += 256) dst[idx] = red[idx];
}

// ---------------- K5: reduce split-K, fold L2 norms + scale, softmax -> bf16 hi|lo [d][96] ----------------
__global__ void k_softmax(const float* __restrict__ Spart,
                          const float* __restrict__ sumsq,
                          const float* __restrict__ scale,
                          u16* __restrict__ attn96){
  int bn = blockIdx.x;                  // b*NH + n
  int b = bn / NH, n = bn - b*NH;
  int i = threadIdx.x;
  if (i >= DH) return;
  const float* sq = sumsq + (size_t)b*C_ + n*DH;
  const float* sk = sumsq + (size_t)B_*C_ + (size_t)b*C_ + n*DH;
  float nq = fmaxf(sqrtf(sq[i]), 1e-12f);
  float sc = scale[n];
  float row[48];
  #pragma unroll
  for (int j = 0; j < DH; ++j){
    float acc = 0.f;
    #pragma unroll
    for (int s = 0; s < SPLIT; ++s)
      acc += Spart[((size_t)(s*(B_*NH) + bn))*2304 + i*48 + j];
    float nk = fmaxf(sqrtf(sk[j]), 1e-12f);
    row[j] = acc / (nq * nk) * sc;
  }
  float m = row[0];
  #pragma unroll
  for (int j = 1; j < DH; ++j) m = fmaxf(m, row[j]);
  float sum = 0.f;
  #pragma unroll
  for (int j = 0; j < DH; ++j){ row[j] = __expf(row[j] - m); sum += row[j]; }
  float inv = 1.f / sum;
  u16* dst = attn96 + ((size_t)bn)*DH*96 + i*96;     // row d=i: hi[0..48) | lo[48..96)
  #pragma unroll
  for (int j = 0; j < DH; ++j){
    float a = row[j] * inv;
    u16 hi = f2bf(a);
    float lo = a - bf2f(hi);
    dst[j]      = hi;
    dst[48 + j] = f2bf(lo);
  }
}

// ---------------- K6: out = attn @ v via MFMA (hi+lo split-K=96), fused LayerNorm ----------------
#define VT_STRIDE 784
__device__ __forceinline__ int vt_off(int p, int ch){
  return p*VT_STRIDE + ((p>>3)<<4) + 2*ch;
}
__global__ __launch_bounds__(256) void k_av_ln2(const u16* __restrict__ qkv,
                                                const u16* __restrict__ attn96,
                                                const float* __restrict__ w2,
                                                const float* __restrict__ b2,
                                                float* __restrict__ out){
  __shared__ u16 vt[(64*VT_STRIDE + 8*16)/2];     // 50304 B
  char* vtb = reinterpret_cast<char*>(vt);
  const int tid = threadIdx.x;
  const int bb = blockIdx.x >> 8;        // 256 tiles per batch
  const int l0 = (blockIdx.x & 255) << 6;
  const u16* vg = qkv + ((size_t)2*B_*C_ + (size_t)bb*C_)*L_ + l0;

  // stage v[c][l0..l0+63] -> vt[p][c] (transposed): channel-pairs, u32 writes
  #pragma unroll
  for (int it = 0; it < 6; ++it){
    int idx = it*256 + tid;            // 0..1535
    int cp = idx >> 3, g = idx & 7;    // cp: channel pair 0..191, g: pixel group
    int c = cp*2;
    uint4 p0 = *reinterpret_cast<const uint4*>(vg + (size_t)c*L_ + g*8);
    uint4 p1 = *reinterpret_cast<const uint4*>(vg + (size_t)(c+1)*L_ + g*8);
    const u16* e0 = reinterpret_cast<const u16*>(&p0);
    const u16* e1 = reinterpret_cast<const u16*>(&p1);
    #pragma unroll
    for (int j = 0; j < 8; ++j){
      int p = g*8 + j;
      u32 packed = ((u32)e0[j]) | (((u32)e1[j]) << 16);
      *reinterpret_cast<u32*>(vtb + vt_off(p, c)) = packed;
    }
  }
  __syncthreads();

  const int w = tid >> 6, lane = tid & 63;
  const int fr = lane & 15, kq = (lane >> 4) * 8;
  const int prow = w*16;
  f32x4 acc[24];
  #pragma unroll
  for (int j = 0; j < 24; ++j) acc[j] = (f32x4){0.f,0.f,0.f,0.f};

  const u16* ab = attn96 + ((size_t)bb*NH)*DH*96;
  #pragma unroll
  for (int n = 0; n < NH; ++n){
    bf16x8 af[3];
    #pragma unroll
    for (int s = 0; s < 3; ++s){
      int ep = s*32 + kq;                       // e' in [0,96)
      int ch = n*DH + (ep >= 48 ? ep - 48 : ep);
      af[s] = *reinterpret_cast<const bf16x8*>(vtb + vt_off(prow + fr, ch));
    }
    #pragma unroll
    for (int jj = 0; jj < 3; ++jj){
      const u16* arow = ab + ((size_t)n*DH + jj*16 + fr)*96;
      #pragma unroll
      for (int s = 0; s < 3; ++s){
        bf16x8 bf = *reinterpret_cast<const bf16x8*>(arow + s*32 + kq);
        acc[n*3+jj] = __builtin_amdgcn_mfma_f32_16x16x32_bf16(af[s], bf, acc[n*3+jj], 0, 0, 0);
      }
    }
  }

  // fused LN2: per-pixel stats (pixel = row), fully intra-wave
  f32x4 s = {0.f,0.f,0.f,0.f}, s2 = {0.f,0.f,0.f,0.f};
  #pragma unroll
  for (int j = 0; j < 24; ++j){ s += acc[j]; s2 += acc[j]*acc[j]; }
  #pragma unroll
  for (int m = 1; m < 16; m <<= 1){
    #pragma unroll
    for (int r = 0; r < 4; ++r){
      s[r]  += __shfl_xor(s[r],  m);
      s2[r] += __shfl_xor(s2[r], m);
    }
  }
  f32x4 mu, rstd;
  #pragma unroll
  for (int r = 0; r < 4; ++r){
    mu[r]   = s[r] * (1.f/C_);
    rstd[r] = rsqrtf(s2[r]*(1.f/C_) - mu[r]*mu[r] + 1e-5f);
  }
  const int pbase = l0 + prow + (lane>>4)*4;
  #pragma unroll
  for (int j = 0; j < 24; ++j){
    int c = j*16 + fr;
    float wc = w2[c], bc = b2[c];
    f32x4 o;
    #pragma unroll
    for (int r = 0; r < 4; ++r)
      o[r] = (acc[j][r] - mu[r]) * rstd[r] * wc + bc;
    *reinterpret_cast<f32x4*>(out + ((size_t)bb*C_ + c)*L_ + pbase) = o;
  }
}

extern "C" void kernel_launch(void* const* d_in, const int* in_sizes, int n_in,
                              void* d_out, int out_size, void* d_ws, size_t ws_size,
                              hipStream_t stream){
  const float* x     = (const float*)d_in[0];
  const float* wq    = (const float*)d_in[1];
  const float* wk    = (const float*)d_in[2];
  const float* wv    = (const float*)d_in[3];
  const float* dwq   = (const float*)d_in[4];
  const float* dwk   = (const float*)d_in[5];
  const float* dwv   = (const float*)d_in[6];
  const float* scale = (const float*)d_in[7];
  const float* ln1w  = (const float*)d_in[8];
  const float* ln1b  = (const float*)d_in[9];
  const float* ln2w  = (const float*)d_in[10];
  const float* ln2b  = (const float*)d_in[11];
  float* out = (float*)d_out;

  char* ws = (char*)d_ws;
  u16*   qkv    = (u16*)ws;                          // [3][B][C][L] bf16  = 150,994,944 B
  u16*   xt     = (u16*)(ws + 150994944);            // [B*L][C] bf16     =  50,331,648 B
  u16*   wc     = (u16*)(ws + 201326592);            // [1152][384] bf16  =     884,736 B
  float* sumsq  = (float*)(ws + 202211328);          // [2][B*C] f32      =      12,288 B
  float* Spart  = (float*)(ws + 202223616);          // [8][32][2304] f32 =   2,359,296 B
  u16*   attn96 = (u16*)(ws + 204582912);            // [32][48][96] u16  =     294,912 B

  k_cvt_w  <<<1728, 256, 0, stream>>>(wq, wk, wv, wc);
  k_ln1    <<<1024, 256, 0, stream>>>(x, ln1w, ln1b, xt);
  k_gemm   <<<2304, 512, 0, stream>>>(wc, xt, qkv);
  k_dwconv <<<3*B_*C_, 256, 0, stream>>>(qkv, dwq, dwk, dwv, sumsq);
  k_qk     <<<SPLIT*B_*NH, 256, 0, stream>>>(qkv, Spart);
  k_softmax<<<B_*NH, 64, 0, stream>>>(Spart, sumsq, scale, attn96);
  k_av_ln2 <<<1024, 256, 0, stream>>>(qkv, attn96, ln2w, ln2b, out);
}